// Round 12
// baseline (346.200 us; speedup 1.0000x reference)
//
#include <hip/hip_runtime.h>
#include <math.h>

#define NA      49104
#define NB      32
#define KPRE    200
#define CAP     2048
#define TAU     2.0f            // static candidate threshold (fallback guards it)
#define NBINS   512             // fallback histogram bins
#define NTHR    1024            // block width (16 waves)
#define NSL     32              // slices per batch (scan role)
#define SLOTCAP 64              // per-(b,c,slice) fixed key slots
#define NQ4     85932           // NA*7/4 float4 per batch row (exact)
#define PERQ4   2688            // NSL*PERQ4 >= NQ4; PERQ4 % 896 == 0, % 7 == 0
#define SCTHR   896             // active scan lanes: stride % 7 == 0
#define NSCAN   (NB * NSL)      // 1024 scan blocks
#define NBLK    (NSCAN + 96 + 32)

// ---- workspace layout (bytes) ----------------------------------------------
#define WS_SDONE 0                        // 32*4
#define WS_DONE  128                      // 32*4   (memset covers [0,256))
#define WS_S10   256                      // 96*10*4  = 3840
#define WS_B10   (WS_S10 + 3840)          // 96*10*16 = 15360
#define WS_CNT   (WS_B10 + 15360)         // 96*32*4  = 12288
#define WS_KEYS  (WS_CNT + 12288)         // 96*2048*8 = 1572864

// ---------------- anchor generation (matches numpy reference) ---------------
__device__ __forceinline__ void anchor_of(int idx, float& cx, float& cy,
                                          float& aw, float& ah) {
    int l, r;
    if (idx < 36864)      { l = 0; r = idx; }
    else if (idx < 46080) { l = 1; r = idx - 36864; }
    else if (idx < 48384) { l = 2; r = idx - 46080; }
    else if (idx < 48960) { l = 3; r = idx - 48384; }
    else                  { l = 4; r = idx - 48960; }
    const int   fss[5]     = {64, 32, 16, 8, 4};
    const int   strides[5] = {8, 16, 32, 64, 128};
    const double areas[5]  = {1024.0, 23104.0, 73984.0, 153664.0, 262144.0};
    int a    = r % 9;
    int cell = r / 9;
    int fs   = fss[l];
    int jx   = cell % fs;
    int iy   = cell / fs;
    cx = ((float)jx + 0.5f) * (float)strides[l];
    cy = ((float)iy + 0.5f) * (float)strides[l];
    int ri = a / 3, si = a % 3;
    double ratio = (ri == 0) ? 0.5 : ((ri == 1) ? 1.0 : 2.0);
    double h = sqrt(areas[l] / ratio);
    double w = areas[l] / h;
    double s = (si == 0) ? 1.0
             : ((si == 1) ? 1.2599210498948732    // 2^(1/3)
                          : 1.5874010519681994);  // 2^(2/3)
    aw = (float)(s * w);
    ah = (float)(s * h);
}

__device__ __forceinline__ int bin_of(float x) {
    int bin = (int)floorf((x + 8.0f) * 32.0f);
    return min(max(bin, 0), NBINS - 1);
}

// order-preserving float->uint map (ascending uint == ascending float)
__device__ __forceinline__ unsigned omap(float x) {
    unsigned u = __float_as_uint(x);
    return u ^ ((u >> 31) ? 0xFFFFFFFFu : 0x80000000u);
}

__device__ __forceinline__ unsigned long long shfl_xor_u64(unsigned long long v,
                                                           int m) {
    unsigned lo = (unsigned)v, hi = (unsigned)(v >> 32);
    lo = __shfl_xor(lo, m, 64);
    hi = __shfl_xor(hi, m, 64);
    return ((unsigned long long)hi << 32) | lo;
}

// ---------------- in-LDS bitonic sort (ascending), NTHR threads -------------
__device__ __forceinline__ void bitonic_sort(unsigned long long* buf, unsigned P,
                                             int tid) {
    for (unsigned k = 2; k <= P; k <<= 1) {
        for (unsigned j = k >> 1; j > 0; j >>= 1) {
            for (unsigned i = tid; i < P; i += NTHR) {
                unsigned ixj = i ^ j;
                if (ixj > i) {
                    bool up = ((i & k) == 0);
                    unsigned long long a = buf[i], bb = buf[ixj];
                    if ((a > bb) == up) { buf[i] = bb; buf[ixj] = a; }
                }
            }
            __syncthreads();
        }
    }
}

// ------ single fused kernel: scan (1024) -> NMS (96) -> merge (32) ----------
__global__ __launch_bounds__(NTHR) void fused_kernel(
        const float* __restrict__ pred, unsigned* __restrict__ sdone,
        unsigned* __restrict__ cnts, unsigned long long* __restrict__ gkeys,
        float* __restrict__ s10, float4* __restrict__ b10,
        unsigned* __restrict__ done, float* __restrict__ out) {
    const int blk = blockIdx.x;
    const int tid = threadIdx.x;
    const int lane = tid & 63;

    // shared pool (scan role reuses keybuf[0..191] as its 3x64 stage)
    __shared__ unsigned long long keybuf[CAP];
    __shared__ unsigned long long sortbuf[512];
    __shared__ float4 boxes[KPRE];
    __shared__ float  scores_s[256];
    __shared__ unsigned long long mask[256][4];
    __shared__ unsigned hist[256];
    __shared__ unsigned hist512[NBINS];
    __shared__ unsigned Lb[NSL], Bb[NSL];
    __shared__ unsigned sMn[16], sMx[16];
    __shared__ unsigned sel_thr, sel_cnt, s_prefB, s_cumB, s_M, s_sh, s_common;
    __shared__ int sT;

    if (blk < NSCAN) {
        // ===================== scan role (b, sl) ============================
        const int b  = blk / NSL;
        const int sl = blk % NSL;
        unsigned long long (*stage)[SLOTCAP] =
            (unsigned long long (*)[SLOTCAP])keybuf;
        unsigned* scnt = hist;                       // [0..2]
        if (tid < 3) scnt[tid] = 0u;
        __syncthreads();

        if (tid < SCTHR) {
            const int p = tid % 7;                   // stride 896 % 7 == 0
            int cls[4];
            #pragma unroll
            for (int j = 0; j < 4; ++j) {
                int f = (4 * p + j) % 7;
                cls[j] = (f >= 4) ? (f - 4) : -1;
            }
            const float4* row = (const float4*)(pred + (size_t)b * NA * 7);
            const int q0 = sl * PERQ4 + tid;
            const int q1 = q0 + SCTHR, q2 = q1 + SCTHR;
            float4 v0, v1, v2;                       // hoisted loads (MLP)
            bool g0 = q0 < NQ4, g1 = q1 < NQ4, g2 = q2 < NQ4;
            if (g0) v0 = row[q0];
            if (g1) v1 = row[q1];
            if (g2) v2 = row[q2];
            #pragma unroll
            for (int it = 0; it < 3; ++it) {
                bool   g = (it == 0) ? g0 : (it == 1) ? g1 : g2;
                float4 v = (it == 0) ? v0 : (it == 1) ? v1 : v2;
                int    q = (it == 0) ? q0 : (it == 1) ? q1 : q2;
                if (!g) continue;
                float vv[4] = {v.x, v.y, v.z, v.w};
                #pragma unroll
                for (int j = 0; j < 4; ++j) {
                    if (cls[j] >= 0 && vv[j] >= TAU) {
                        int e = (q << 2) + j;
                        int n = e / 7;
                        unsigned u = __float_as_uint(vv[j]) | 0x80000000u;
                        unsigned long long key =
                            ((unsigned long long)(~u) << 32) | (unsigned)n;
                        int c = cls[j];
                        unsigned pos = atomicAdd(&scnt[c], 1u);
                        if (pos < SLOTCAP) stage[c][pos] = key;
                        // overflow: count > SLOTCAP forces consumer fallback
                    }
                }
            }
        }
        __syncthreads();

        if (tid < 3) cnts[(b * 3 + tid) * NSL + sl] = scnt[tid];
        #pragma unroll
        for (int c = 0; c < 3; ++c) {
            unsigned n = min(scnt[c], (unsigned)SLOTCAP);
            unsigned long long* dst =
                gkeys + ((size_t)(b * 3 + c) * NSL + sl) * SLOTCAP;
            for (unsigned i = tid; i < n; i += NTHR) dst[i] = stage[c][i];
        }
        __threadfence();                 // each thread publishes its stores
        __syncthreads();
        if (tid == 0)
            __hip_atomic_fetch_add(&sdone[b], 1u, __ATOMIC_RELEASE,
                                   __HIP_MEMORY_SCOPE_AGENT);
        return;
    }

    if (blk >= NSCAN + 96) {
        // ===================== merge role ===================================
        const int b = blk - (NSCAN + 96);
        if (tid == 0) {
            while (__hip_atomic_load(&done[b], __ATOMIC_ACQUIRE,
                                     __HIP_MEMORY_SCOPE_AGENT) < 3u)
                __builtin_amdgcn_s_sleep(8);
        }
        __syncthreads();
        __threadfence();

        if (tid < 64) {
            float s = (tid < 30) ? s10[b * 30 + tid] : -2.0f;
            float* ob = out + b * 40;
            float* os = out + 1280 + b * 10;
            float* oc = out + 1600 + b * 10;
            float* ov = out + 1920 + b;
            int valid = 0;
            for (int k = 0; k < 10; ++k) {
                unsigned u = __float_as_uint(s);
                unsigned o = (u >> 31) ? ~u : (u | 0x80000000u);
                unsigned long long key =
                    ((unsigned long long)o << 6) | (unsigned)(63 - tid);
                #pragma unroll
                for (int off = 1; off < 64; off <<= 1) {
                    unsigned long long k2 = __shfl_xor(key, off, 64);
                    key = (k2 > key) ? k2 : key;
                }
                int t = 63 - (int)(key & 63ULL);
                float best = __shfl(s, t, 64);
                bool v = best > 0.0f;
                if (tid == t) {
                    float4 bb = v ? b10[b * 30 + t] : make_float4(0, 0, 0, 0);
                    ob[k * 4 + 0] = bb.x; ob[k * 4 + 1] = bb.y;
                    ob[k * 4 + 2] = bb.z; ob[k * 4 + 3] = bb.w;
                    os[k] = v ? best : 0.0f;
                    oc[k] = v ? (float)(t / 10) : 0.0f;
                    s = -2.0f;
                }
                valid += v ? 1 : 0;
            }
            if (tid == 0) ov[0] = (float)valid;
        }
        return;
    }

    // ==================== class-NMS role (blk96 = b*3 + c) ===================
    const int blk96 = blk - NSCAN;
    const int b = blk96 / 3;
    const int c = blk96 % 3;

    if (tid == 0) {
        while (__hip_atomic_load(&sdone[b], __ATOMIC_ACQUIRE,
                                 __HIP_MEMORY_SCOPE_AGENT) < (unsigned)NSL)
            __builtin_amdgcn_s_sleep(8);
    }
    __syncthreads();
    __threadfence();

    if (tid < 256) hist[tid] = 0u;
    if (tid == 0) sel_cnt = 0u;

    // ---- slice-count prefix (wave 0, lanes 0..31) --------------------------
    if (tid < NSL) {
        unsigned L  = cnts[blk96 * NSL + tid];
        unsigned Lc = min(L, (unsigned)SLOTCAP);
        unsigned pre = Lc;
        #pragma unroll
        for (int off = 1; off < NSL; off <<= 1) {
            unsigned v = __shfl_up(pre, off, 64);
            if (tid >= off) pre += v;
        }
        Lb[tid] = Lc;
        Bb[tid] = pre - Lc;
        unsigned long long ob = __ballot(L > SLOTCAP);
        if (tid == NSL - 1) s_M = pre;
        if (tid == 0)       s_common = (ob == 0ULL) ? 1u : 0u;
    }
    __syncthreads();

    const unsigned M0 = s_M;
    const bool common = s_common && M0 >= KPRE && M0 <= CAP;

    if (common) {
        // gather fixed slots -> compact keybuf ([0,M) fully written)
        const unsigned long long* src = gkeys + (size_t)blk96 * NSL * SLOTCAP;
        #pragma unroll
        for (int u = 0; u < NSL * SLOTCAP / NTHR; ++u) {
            int i = u * NTHR + tid;
            int sl = i >> 6, k = i & (SLOTCAP - 1);
            if ((unsigned)k < Lb[sl]) keybuf[Bb[sl] + k] = src[i];
        }
    } else {
        // ---- exact in-block fallback: histogram threshold + recollect ------
        const float* col = pred + (size_t)b * NA * 7 + 4 + c;
        for (int i = tid; i < NBINS; i += NTHR) hist512[i] = 0u;
        if (tid == 0) s_M = 0u;
        __syncthreads();
        for (int n = tid; n < NA; n += NTHR)
            atomicAdd(&hist512[bin_of(col[(size_t)n * 7])], 1u);
        __syncthreads();
        if (tid < 64) {                                 // wave-0 suffix scan
            unsigned h[8]; unsigned lsum = 0;
            #pragma unroll
            for (int k = 0; k < 8; ++k) { h[k] = hist512[tid*8+k]; lsum += h[k]; }
            unsigned suf = lsum;
            #pragma unroll
            for (int off = 1; off < 64; off <<= 1) {
                unsigned v = __shfl_down(suf, off, 64);
                if (tid < 64 - off) suf += v;
            }
            unsigned acc = suf - lsum;                  // bins above my range
            #pragma unroll
            for (int k = 7; k >= 0; --k) {
                unsigned na = acc + h[k];
                if (na >= KPRE && acc < KPRE) sT = max(tid*8 + k - 1, 0);
                acc = na;
            }
        }
        __syncthreads();
        const int T = sT;
        for (int it = 0; it < 48; ++it) {               // ballot-aggregated
            int n = it * NTHR + tid;
            float x = (n < NA) ? col[(size_t)n * 7] : -1e30f;
            bool ok = (n < NA) && (bin_of(x) >= T);
            unsigned long long mb = __ballot(ok);
            unsigned cnt = (unsigned)__popcll(mb);
            if (cnt) {
                unsigned basep = 0;
                if (lane == 0) basep = atomicAdd(&s_M, cnt);
                basep = __shfl(basep, 0, 64);
                if (ok) {
                    unsigned off = (unsigned)__popcll(mb & ((1ULL << lane) - 1ULL));
                    unsigned pos = basep + off;
                    if (pos < CAP)
                        keybuf[pos] =
                            ((unsigned long long)(~omap(x)) << 32) | (unsigned)n;
                }
            }
        }
        __syncthreads();
    }
    const unsigned M = min(s_M, (unsigned)CAP);

    // ---- exact rank-KPRE selection: adaptive two-level digit hist ----------
    if (M > KPRE) {
        {   // top-byte uniformity probe
            unsigned mn = 0xFFu, mx = 0u;
            for (int i = tid; i < (int)M; i += NTHR) {
                unsigned h = (unsigned)(keybuf[i] >> 56);
                mn = min(mn, h); mx = max(mx, h);
            }
            #pragma unroll
            for (int off = 1; off < 64; off <<= 1) {
                mn = min(mn, (unsigned)__shfl_xor((int)mn, off, 64));
                mx = max(mx, (unsigned)__shfl_xor((int)mx, off, 64));
            }
            if (lane == 0) { sMn[tid >> 6] = mn; sMx[tid >> 6] = mx; }
        }
        __syncthreads();
        if (tid == 0) {
            unsigned mn = 0xFFu, mx = 0u;
            #pragma unroll
            for (int w = 0; w < NTHR / 64; ++w) {
                mn = min(mn, sMn[w]); mx = max(mx, sMx[w]);
            }
            s_sh = (mn == mx) ? 40u : 48u;
        }
        __syncthreads();
        const unsigned sh = s_sh;

        for (int i = tid; i < (int)M; i += NTHR)
            atomicAdd(&hist[(unsigned)(keybuf[i] >> (sh + 8)) & 0xFFu], 1u);
        __syncthreads();
        if (tid < 64) {                                 // wave-0 prefix scan
            unsigned h0 = hist[tid*4],   h1 = hist[tid*4+1];
            unsigned h2 = hist[tid*4+2], h3 = hist[tid*4+3];
            unsigned lsum = h0 + h1 + h2 + h3;
            unsigned pre = lsum;
            #pragma unroll
            for (int off = 1; off < 64; off <<= 1) {
                unsigned v = __shfl_up(pre, off, 64);
                if (tid >= off) pre += v;
            }
            unsigned acc = pre - lsum;                  // bins below my range
            if (acc < KPRE) {
                if      (acc + h0            >= KPRE) { s_prefB = tid*4;   s_cumB = acc; }
                else if (acc + h0 + h1       >= KPRE) { s_prefB = tid*4+1; s_cumB = acc+h0; }
                else if (acc + h0 + h1 + h2  >= KPRE) { s_prefB = tid*4+2; s_cumB = acc+h0+h1; }
                else if (acc + lsum          >= KPRE) { s_prefB = tid*4+3; s_cumB = acc+h0+h1+h2; }
            }
        }
        __syncthreads();
        const unsigned B = s_prefB, before = s_cumB;
        if (tid < 256) hist[tid] = 0u;
        __syncthreads();
        for (int i = tid; i < (int)M; i += NTHR) {
            unsigned long long key = keybuf[i];
            if (((unsigned)(key >> (sh + 8)) & 0xFFu) == B)
                atomicAdd(&hist[(unsigned)(key >> sh) & 0xFFu], 1u);
        }
        __syncthreads();
        if (tid < 64) {
            const unsigned target = KPRE - before;      // >= 1
            unsigned h0 = hist[tid*4],   h1 = hist[tid*4+1];
            unsigned h2 = hist[tid*4+2], h3 = hist[tid*4+3];
            unsigned lsum = h0 + h1 + h2 + h3;
            unsigned pre = lsum;
            #pragma unroll
            for (int off = 1; off < 64; off <<= 1) {
                unsigned v = __shfl_up(pre, off, 64);
                if (tid >= off) pre += v;
            }
            unsigned acc = pre - lsum;
            if (acc < target) {
                unsigned b2 = 256;
                if      (acc + h0           >= target) b2 = tid*4;
                else if (acc + h0 + h1      >= target) b2 = tid*4+1;
                else if (acc + h0 + h1 + h2 >= target) b2 = tid*4+2;
                else if (acc + lsum         >= target) b2 = tid*4+3;
                if (b2 < 256) sel_thr = (B << 8) | b2;
            }
        }
        __syncthreads();
        const unsigned thr = sel_thr;
        for (int i = tid; i < (int)M; i += NTHR) {
            unsigned long long key = keybuf[i];
            if (((unsigned)(key >> sh) & 0xFFFFu) <= thr) {
                unsigned pos = atomicAdd(&sel_cnt, 1u);
                if (pos < 512) sortbuf[pos] = key;
            }
        }
        __syncthreads();
    } else {
        for (int i = tid; i < (int)M; i += NTHR) sortbuf[i] = keybuf[i];
        if (tid == 0) sel_cnt = M;
        __syncthreads();
    }

    // ---- sort top candidates (ascending key == score desc, idx asc) --------
    const unsigned C2 = sel_cnt;
    unsigned long long* sorted;
    if (C2 <= 256) {
        unsigned long long v = ~0ULL;
        if (tid < 256) {
            v = (tid < (int)C2) ? sortbuf[tid] : ~0ULL;
            #pragma unroll
            for (unsigned k = 2; k <= 64; k <<= 1) {
                for (unsigned j = k >> 1; j > 0; j >>= 1) {
                    unsigned long long o = shfl_xor_u64(v, (int)j);
                    bool tm = (((tid & k) == 0) == ((tid & j) == 0));
                    v = tm ? (v < o ? v : o) : (v > o ? v : o);
                }
            }
        }
        __syncthreads();
        if (tid < 256) sortbuf[tid] = v;
        __syncthreads();
        if (tid < 256) {           // k = 128: j = 64 via LDS, then shfl
            unsigned long long o = sortbuf[tid ^ 64];
            bool tm = (((tid & 128) == 0) == ((tid & 64) == 0));
            v = tm ? (v < o ? v : o) : (v > o ? v : o);
            #pragma unroll
            for (unsigned j = 32; j > 0; j >>= 1) {
                unsigned long long o2 = shfl_xor_u64(v, (int)j);
                bool t2 = (((tid & 128) == 0) == ((tid & j) == 0));
                v = t2 ? (v < o2 ? v : o2) : (v > o2 ? v : o2);
            }
        }
        __syncthreads();
        if (tid < 256) sortbuf[tid] = v;
        __syncthreads();
        if (tid < 256) {           // k = 256: j = 128 via LDS
            unsigned long long o = sortbuf[tid ^ 128];
            bool tm = ((tid & 128) == 0);
            v = tm ? (v < o ? v : o) : (v > o ? v : o);
        }
        __syncthreads();
        if (tid < 256) sortbuf[tid] = v;
        __syncthreads();
        if (tid < 256) {           // k = 256: j = 64 via LDS, then shfl
            unsigned long long o = sortbuf[tid ^ 64];
            bool tm = ((tid & 64) == 0);
            v = tm ? (v < o ? v : o) : (v > o ? v : o);
            #pragma unroll
            for (unsigned j = 32; j > 0; j >>= 1) {
                unsigned long long o2 = shfl_xor_u64(v, (int)j);
                bool t2 = ((tid & j) == 0);
                v = t2 ? (v < o2 ? v : o2) : (v > o2 ? v : o2);
            }
        }
        __syncthreads();
        if (tid < 256) sortbuf[tid] = v;
        __syncthreads();
        sorted = sortbuf;
    } else if (C2 <= 512) {
        for (int i = (int)C2 + tid; i < 512; i += NTHR) sortbuf[i] = ~0ULL;
        __syncthreads();
        bitonic_sort(sortbuf, 512, tid);
        sorted = sortbuf;
    } else {                                   // adversarial tie storm
        for (int i = (int)M + tid; i < CAP; i += NTHR) keybuf[i] = ~0ULL;
        __syncthreads();
        bitonic_sort(keybuf, CAP, tid);
        sorted = keybuf;
    }

    // ---- decode top-200 ----------------------------------------------------
    if (tid < KPRE) {
        unsigned long long key = sorted[tid];
        if (key != ~0ULL) {
            unsigned n = (unsigned)key;
            unsigned v = ~(unsigned)(key >> 32);
            v = (v >> 31) ? (v ^ 0x80000000u) : ~v;
            float x  = __uint_as_float(v);
            float sc = 1.0f / (1.0f + expf(-x));
            const float* bp = pred + (size_t)b * NA * 7 + (size_t)n * 7;
            float d0 = bp[0] * 0.1f, d1 = bp[1] * 0.1f;
            float d2 = bp[2] * 0.2f, d3 = bp[3] * 0.2f;
            float cx, cy, aw, ah;
            anchor_of((int)n, cx, cy, aw, ah);
            float xx = d0 * aw + cx;
            float yy = d1 * ah + cy;
            float ww = expf(d2) * aw;
            float hh = expf(d3) * ah;
            boxes[tid]    = make_float4(xx - ww * 0.5f, yy - hh * 0.5f,
                                        xx + ww * 0.5f, yy + hh * 0.5f);
            scores_s[tid] = sc;
        } else {
            boxes[tid]    = make_float4(0, 0, 0, 0);
            scores_s[tid] = -1.0f;
        }
    } else if (tid < 256) {
        scores_s[tid] = -1.0f;
    }
    __syncthreads();

    // ---- pairwise IoU bitmasks: (row, chunk) 2D decomposition --------------
    {
        const int row = tid & 255;
        const int cb  = tid >> 8;
        unsigned long long m = 0ULL;
        if (row < KPRE) {
            const int lo = cb * 64;
            const int hi = min(lo + 64, KPRE);
            float4 bi = boxes[row];
            float areai = (bi.z - bi.x) * (bi.w - bi.y);
            for (int j = max(row + 1, lo); j < hi; ++j) {
                float4 bj = boxes[j];
                float x1 = fmaxf(bi.x, bj.x), y1 = fmaxf(bi.y, bj.y);
                float x2 = fminf(bi.z, bj.z), y2 = fminf(bi.w, bj.w);
                float iw = fmaxf(x2 - x1, 0.0f), ih = fmaxf(y2 - y1, 0.0f);
                float inter = iw * ih;
                float areaj = (bj.z - bj.x) * (bj.w - bj.y);
                float uni   = fmaxf(areai + areaj - inter, 1e-8f);
                if (inter / uni > 0.5f) m |= 1ULL << (j - lo);
            }
        }
        mask[row][cb] = m;
    }
    __syncthreads();

    // ---- wave-parallel greedy sweep (wave 0), exact sequential semantics ---
    if (tid < 64) {
        unsigned long long keep[4];
        #pragma unroll
        for (int cb = 0; cb < 4; ++cb)
            keep[cb] = __ballot(scores_s[cb * 64 + lane] >= 0.05f);

        #pragma unroll
        for (int cb = 0; cb < 4; ++cb) {
            unsigned long long mw_self = mask[cb * 64 + lane][cb];
            unsigned long long kw   = keep[cb];
            unsigned long long work = kw & __ballot(mw_self != 0ULL);
            while (work) {                       // uniform loop
                int t = __ffsll(work) - 1;
                work &= work - 1;
                if ((kw >> t) & 1ULL) {
                    unsigned long long m = __shfl(mw_self, t, 64);
                    kw   &= ~m;
                    work &= ~m;
                }
            }
            keep[cb] = kw;
            #pragma unroll
            for (int w = cb + 1; w < 4; ++w) {
                unsigned long long myw = mask[cb * 64 + lane][w];
                if ((__ballot(myw != 0ULL) & kw) == 0ULL) continue;
                unsigned long long contrib = ((kw >> lane) & 1ULL) ? myw : 0ULL;
                #pragma unroll
                for (int off = 1; off < 64; off <<= 1)
                    contrib |= __shfl_xor(contrib, off, 64);
                keep[w] &= ~contrib;
            }
        }

        if (lane == 0) {
            int k = 0;
            #pragma unroll
            for (int cb = 0; cb < 4; ++cb) {
                unsigned long long kw = keep[cb];
                while (kw && k < 10) {
                    int t = __ffsll(kw) - 1; kw &= kw - 1;
                    int i = cb * 64 + t;
                    s10[blk96 * 10 + k] = scores_s[i];
                    b10[blk96 * 10 + k] = boxes[i];
                    ++k;
                }
            }
            #pragma unroll
            for (int cb = 0; cb < 4; ++cb) {
                unsigned long long nk = ~keep[cb];
                if (cb == 3) nk &= 0xFFULL;          // i < 200
                while (nk && k < 10) {
                    int t = __ffsll(nk) - 1; nk &= nk - 1;
                    int i = cb * 64 + t;
                    s10[blk96 * 10 + k] = -1.0f;
                    b10[blk96 * 10 + k] = boxes[i];
                    ++k;
                }
            }
            __threadfence();
            __hip_atomic_fetch_add(&done[b], 1u, __ATOMIC_RELEASE,
                                   __HIP_MEMORY_SCOPE_AGENT);
        }
    }
}

// ---------------- launch ----------------------------------------------------
extern "C" void kernel_launch(void* const* d_in, const int* in_sizes, int n_in,
                              void* d_out, int out_size, void* d_ws, size_t ws_size,
                              hipStream_t stream) {
    const float* pred = (const float*)d_in[1];   // d_in[0] = images (shape only)

    char* ws = (char*)d_ws;
    unsigned*            sdone = (unsigned*)           (ws + WS_SDONE);
    unsigned*            done  = (unsigned*)           (ws + WS_DONE);
    float*               s10   = (float*)              (ws + WS_S10);
    float4*              b10   = (float4*)             (ws + WS_B10);
    unsigned*            cnts  = (unsigned*)           (ws + WS_CNT);
    unsigned long long*  keys  = (unsigned long long*) (ws + WS_KEYS);

    hipMemsetAsync(ws, 0, 256, stream);          // sdone + done tickets
    fused_kernel<<<NBLK, NTHR, 0, stream>>>(pred, sdone, cnts, keys,
                                            s10, b10, done, (float*)d_out);
}

// Round 13
// 98.267 us; speedup vs baseline: 3.5230x; 3.5230x over previous
//
#include <hip/hip_runtime.h>
#include <math.h>

#define NA      49104
#define NB      32
#define KPRE    200
#define CAP     2048
#define TAU     2.0f            // static candidate threshold (fallback guards it)
#define NBINS   512             // fallback histogram bins
#define NTHR    1024            // block width (16 waves)
#define NQ4     85932           // NA*7/4 float4 per batch row (exact)
#define SEG     21483           // NQ4/4 exactly; SEG % 7 == 0 (7*3069)
#define SCTHR   896             // active scan lanes: stride % 7 == 0
#define NITS    24              // ceil(SEG / SCTHR)
#define STGCAP  640             // LDS stage slots per class (mean ~280, 21 sigma)

// ---- workspace layout (bytes); memset zeroes [0, 640) ----------------------
#define WS_SDONE 0                        // 32*4
#define WS_DONE  128                      // 32*4
#define WS_GCNT  256                      // 96*4 = 384 (ends at 640)
#define WS_S10   640                      // 96*10*4  = 3840
#define WS_B10   4480                     // 96*10*16 = 15360 (16B aligned)
#define WS_KEYS  19840                    // 96*2048*8 = 1572864

// ---------------- anchor generation (matches numpy reference) ---------------
__device__ __forceinline__ void anchor_of(int idx, float& cx, float& cy,
                                          float& aw, float& ah) {
    int l, r;
    if (idx < 36864)      { l = 0; r = idx; }
    else if (idx < 46080) { l = 1; r = idx - 36864; }
    else if (idx < 48384) { l = 2; r = idx - 46080; }
    else if (idx < 48960) { l = 3; r = idx - 48384; }
    else                  { l = 4; r = idx - 48960; }
    const int   fss[5]     = {64, 32, 16, 8, 4};
    const int   strides[5] = {8, 16, 32, 64, 128};
    const double areas[5]  = {1024.0, 23104.0, 73984.0, 153664.0, 262144.0};
    int a    = r % 9;
    int cell = r / 9;
    int fs   = fss[l];
    int jx   = cell % fs;
    int iy   = cell / fs;
    cx = ((float)jx + 0.5f) * (float)strides[l];
    cy = ((float)iy + 0.5f) * (float)strides[l];
    int ri = a / 3, si = a % 3;
    double ratio = (ri == 0) ? 0.5 : ((ri == 1) ? 1.0 : 2.0);
    double h = sqrt(areas[l] / ratio);
    double w = areas[l] / h;
    double s = (si == 0) ? 1.0
             : ((si == 1) ? 1.2599210498948732    // 2^(1/3)
                          : 1.5874010519681994);  // 2^(2/3)
    aw = (float)(s * w);
    ah = (float)(s * h);
}

__device__ __forceinline__ int bin_of(float x) {
    int bin = (int)floorf((x + 8.0f) * 32.0f);
    return min(max(bin, 0), NBINS - 1);
}

// order-preserving float->uint map (ascending uint == ascending float)
__device__ __forceinline__ unsigned omap(float x) {
    unsigned u = __float_as_uint(x);
    return u ^ ((u >> 31) ? 0xFFFFFFFFu : 0x80000000u);
}

__device__ __forceinline__ unsigned long long shfl_xor_u64(unsigned long long v,
                                                           int m) {
    unsigned lo = (unsigned)v, hi = (unsigned)(v >> 32);
    lo = __shfl_xor(lo, m, 64);
    hi = __shfl_xor(hi, m, 64);
    return ((unsigned long long)hi << 32) | lo;
}

// ---------------- in-LDS bitonic sort (ascending), NTHR threads -------------
__device__ __forceinline__ void bitonic_sort(unsigned long long* buf, unsigned P,
                                             int tid) {
    for (unsigned k = 2; k <= P; k <<= 1) {
        for (unsigned j = k >> 1; j > 0; j >>= 1) {
            for (unsigned i = tid; i < P; i += NTHR) {
                unsigned ixj = i ^ j;
                if (ixj > i) {
                    bool up = ((i & k) == 0);
                    unsigned long long a = buf[i], bb = buf[ixj];
                    if ((a > bb) == up) { buf[i] = bb; buf[ixj] = a; }
                }
            }
            __syncthreads();
        }
    }
}

// ------ ONE kernel, 128 co-resident blocks: each scans a row segment, -------
// ------ then 96 do class-NMS and 32 do the final merge ----------------------
__global__ __launch_bounds__(NTHR) void fused_kernel(
        const float* __restrict__ pred, unsigned* __restrict__ sdone,
        unsigned* __restrict__ gcnt, unsigned long long* __restrict__ gkeys,
        float* __restrict__ s10, float4* __restrict__ b10,
        unsigned* __restrict__ done, float* __restrict__ out) {
    const int blk = blockIdx.x;            // 0..95 class-NMS, 96..127 merge
    const int tid = threadIdx.x;
    const int lane = tid & 63;
    const bool is_merge = (blk >= 96);
    const int b   = is_merge ? (blk - 96) : (blk / 3);
    const int seg = is_merge ? 3 : (blk % 3);

    __shared__ unsigned long long keybuf[CAP];     // scan stage reuses this
    __shared__ unsigned long long sortbuf[512];
    __shared__ float4 boxes[KPRE];
    __shared__ float  scores_s[256];
    __shared__ unsigned long long mask[256][4];
    __shared__ unsigned hist[256];                 // scan scnt reuses [0..2]
    __shared__ unsigned hist512[NBINS];
    __shared__ unsigned sMn[16], sMx[16];
    __shared__ unsigned sbase[3];
    __shared__ unsigned sel_thr, sel_cnt, s_prefB, s_cumB, s_M, s_sh;
    __shared__ int sT;

    // ===================== phase A: coalesced segment scan ===================
    {
        unsigned long long (*stage)[STGCAP] =
            (unsigned long long (*)[STGCAP])keybuf;
        unsigned* scnt = hist;                     // [0..2]
        if (tid < 3) scnt[tid] = 0u;
        __syncthreads();

        if (tid < SCTHR) {
            const int p = tid % 7;                 // SEG%7==0, stride 896%7==0
            int cls[4];
            #pragma unroll
            for (int j = 0; j < 4; ++j) {
                int f = (4 * p + j) % 7;
                cls[j] = (f >= 4) ? (f - 4) : -1;
            }
            const float4* row = (const float4*)(pred + (size_t)b * NA * 7);
            const int qend = seg * SEG + SEG;
            int q = seg * SEG + tid;
            for (int it = 0; it < NITS; ++it, q += SCTHR) {
                if (q >= qend) break;
                float4 v = row[q];
                float vv[4] = {v.x, v.y, v.z, v.w};
                #pragma unroll
                for (int j = 0; j < 4; ++j) {
                    if (cls[j] >= 0 && vv[j] >= TAU) {
                        int e = (q << 2) + j;
                        int n = e / 7;
                        unsigned u = __float_as_uint(vv[j]) | 0x80000000u;
                        unsigned long long key =
                            ((unsigned long long)(~u) << 32) | (unsigned)n;
                        int c = cls[j];
                        unsigned pos = atomicAdd(&scnt[c], 1u);
                        if (pos < STGCAP) stage[c][pos] = key;
                        else {                         // rare: direct publish
                            unsigned gp = atomicAdd(&gcnt[b * 3 + c], 1u);
                            if (gp < CAP)
                                gkeys[(size_t)(b * 3 + c) * CAP + gp] = key;
                        }
                    }
                }
            }
        }
        __syncthreads();

        if (tid < 3)
            sbase[tid] = atomicAdd(&gcnt[b * 3 + tid],
                                   min(scnt[tid], (unsigned)STGCAP));
        __syncthreads();
        #pragma unroll
        for (int c = 0; c < 3; ++c) {
            unsigned n = min(scnt[c], (unsigned)STGCAP);
            unsigned base = sbase[c];
            unsigned long long* dst = gkeys + (size_t)(b * 3 + c) * CAP;
            for (unsigned i = tid; i < n; i += NTHR) {
                unsigned pos = base + i;
                if (pos < CAP) dst[pos] = stage[c][i];
            }
        }
        __threadfence();                 // wave-level release of key stores
        __syncthreads();
        if (tid == 0)
            __hip_atomic_fetch_add(&sdone[b], 1u, __ATOMIC_RELEASE,
                                   __HIP_MEMORY_SCOPE_AGENT);
    }

    if (is_merge) {
        // ===================== merge role ===================================
        if (tid == 0) {
            while (__hip_atomic_load(&done[b], __ATOMIC_ACQUIRE,
                                     __HIP_MEMORY_SCOPE_AGENT) < 3u)
                __builtin_amdgcn_s_sleep(32);
        }
        __syncthreads();

        if (tid < 64) {
            float s = (tid < 30) ? s10[b * 30 + tid] : -2.0f;
            float* ob = out + b * 40;
            float* os = out + 1280 + b * 10;
            float* oc = out + 1600 + b * 10;
            float* ov = out + 1920 + b;
            int valid = 0;
            for (int k = 0; k < 10; ++k) {
                unsigned u = __float_as_uint(s);
                unsigned o = (u >> 31) ? ~u : (u | 0x80000000u);
                unsigned long long key =
                    ((unsigned long long)o << 6) | (unsigned)(63 - tid);
                #pragma unroll
                for (int off = 1; off < 64; off <<= 1) {
                    unsigned long long k2 = __shfl_xor(key, off, 64);
                    key = (k2 > key) ? k2 : key;
                }
                int t = 63 - (int)(key & 63ULL);
                float best = __shfl(s, t, 64);
                bool v = best > 0.0f;
                if (tid == t) {
                    float4 bb = v ? b10[b * 30 + t] : make_float4(0, 0, 0, 0);
                    ob[k * 4 + 0] = bb.x; ob[k * 4 + 1] = bb.y;
                    ob[k * 4 + 2] = bb.z; ob[k * 4 + 3] = bb.w;
                    os[k] = v ? best : 0.0f;
                    oc[k] = v ? (float)(t / 10) : 0.0f;
                    s = -2.0f;
                }
                valid += v ? 1 : 0;
            }
            if (tid == 0) ov[0] = (float)valid;
        }
        return;
    }

    // ==================== class-NMS role (blk = b*3 + c) =====================
    const int c = seg;                    // for NMS blocks, seg == class

    if (tid == 0) {
        while (__hip_atomic_load(&sdone[b], __ATOMIC_ACQUIRE,
                                 __HIP_MEMORY_SCOPE_AGENT) < 4u)
            __builtin_amdgcn_s_sleep(32);
        s_M = gcnt[blk];                  // total candidates for (b,c)
    }
    __syncthreads();

    if (tid < 256) hist[tid] = 0u;
    if (tid == 0) sel_cnt = 0u;
    __syncthreads();

    const unsigned M0 = s_M;
    const bool common = (M0 >= KPRE && M0 <= CAP);

    if (common) {
        const unsigned long long* src = gkeys + (size_t)blk * CAP;
        for (int i = tid; i < (int)M0; i += NTHR) keybuf[i] = src[i];
    } else {
        // ---- exact in-block fallback: histogram threshold + recollect ------
        const float* col = pred + (size_t)b * NA * 7 + 4 + c;
        for (int i = tid; i < NBINS; i += NTHR) hist512[i] = 0u;
        if (tid == 0) s_M = 0u;
        __syncthreads();
        for (int n = tid; n < NA; n += NTHR)
            atomicAdd(&hist512[bin_of(col[(size_t)n * 7])], 1u);
        __syncthreads();
        if (tid < 64) {                                 // wave-0 suffix scan
            unsigned h[8]; unsigned lsum = 0;
            #pragma unroll
            for (int k = 0; k < 8; ++k) { h[k] = hist512[tid*8+k]; lsum += h[k]; }
            unsigned suf = lsum;
            #pragma unroll
            for (int off = 1; off < 64; off <<= 1) {
                unsigned v = __shfl_down(suf, off, 64);
                if (tid < 64 - off) suf += v;
            }
            unsigned acc = suf - lsum;                  // bins above my range
            #pragma unroll
            for (int k = 7; k >= 0; --k) {
                unsigned na = acc + h[k];
                if (na >= KPRE && acc < KPRE) sT = max(tid*8 + k - 1, 0);
                acc = na;
            }
        }
        __syncthreads();
        const int T = sT;
        for (int it = 0; it < 48; ++it) {               // ballot-aggregated
            int n = it * NTHR + tid;
            float x = (n < NA) ? col[(size_t)n * 7] : -1e30f;
            bool ok = (n < NA) && (bin_of(x) >= T);
            unsigned long long mb = __ballot(ok);
            unsigned cnt = (unsigned)__popcll(mb);
            if (cnt) {
                unsigned basep = 0;
                if (lane == 0) basep = atomicAdd(&s_M, cnt);
                basep = __shfl(basep, 0, 64);
                if (ok) {
                    unsigned off = (unsigned)__popcll(mb & ((1ULL << lane) - 1ULL));
                    unsigned pos = basep + off;
                    if (pos < CAP)
                        keybuf[pos] =
                            ((unsigned long long)(~omap(x)) << 32) | (unsigned)n;
                }
            }
        }
        __syncthreads();
    }
    const unsigned M = min(s_M, (unsigned)CAP);

    // ---- exact rank-KPRE selection: adaptive two-level digit hist ----------
    if (M > KPRE) {
        {   // top-byte uniformity probe
            unsigned mn = 0xFFu, mx = 0u;
            for (int i = tid; i < (int)M; i += NTHR) {
                unsigned h = (unsigned)(keybuf[i] >> 56);
                mn = min(mn, h); mx = max(mx, h);
            }
            #pragma unroll
            for (int off = 1; off < 64; off <<= 1) {
                mn = min(mn, (unsigned)__shfl_xor((int)mn, off, 64));
                mx = max(mx, (unsigned)__shfl_xor((int)mx, off, 64));
            }
            if (lane == 0) { sMn[tid >> 6] = mn; sMx[tid >> 6] = mx; }
        }
        __syncthreads();
        if (tid == 0) {
            unsigned mn = 0xFFu, mx = 0u;
            #pragma unroll
            for (int w = 0; w < NTHR / 64; ++w) {
                mn = min(mn, sMn[w]); mx = max(mx, sMx[w]);
            }
            s_sh = (mn == mx) ? 40u : 48u;
        }
        __syncthreads();
        const unsigned sh = s_sh;

        for (int i = tid; i < (int)M; i += NTHR)
            atomicAdd(&hist[(unsigned)(keybuf[i] >> (sh + 8)) & 0xFFu], 1u);
        __syncthreads();
        if (tid < 64) {                                 // wave-0 prefix scan
            unsigned h0 = hist[tid*4],   h1 = hist[tid*4+1];
            unsigned h2 = hist[tid*4+2], h3 = hist[tid*4+3];
            unsigned lsum = h0 + h1 + h2 + h3;
            unsigned pre = lsum;
            #pragma unroll
            for (int off = 1; off < 64; off <<= 1) {
                unsigned v = __shfl_up(pre, off, 64);
                if (tid >= off) pre += v;
            }
            unsigned acc = pre - lsum;                  // bins below my range
            if (acc < KPRE) {
                if      (acc + h0            >= KPRE) { s_prefB = tid*4;   s_cumB = acc; }
                else if (acc + h0 + h1       >= KPRE) { s_prefB = tid*4+1; s_cumB = acc+h0; }
                else if (acc + h0 + h1 + h2  >= KPRE) { s_prefB = tid*4+2; s_cumB = acc+h0+h1; }
                else if (acc + lsum          >= KPRE) { s_prefB = tid*4+3; s_cumB = acc+h0+h1+h2; }
            }
        }
        __syncthreads();
        const unsigned B = s_prefB, before = s_cumB;
        if (tid < 256) hist[tid] = 0u;
        __syncthreads();
        for (int i = tid; i < (int)M; i += NTHR) {
            unsigned long long key = keybuf[i];
            if (((unsigned)(key >> (sh + 8)) & 0xFFu) == B)
                atomicAdd(&hist[(unsigned)(key >> sh) & 0xFFu], 1u);
        }
        __syncthreads();
        if (tid < 64) {
            const unsigned target = KPRE - before;      // >= 1
            unsigned h0 = hist[tid*4],   h1 = hist[tid*4+1];
            unsigned h2 = hist[tid*4+2], h3 = hist[tid*4+3];
            unsigned lsum = h0 + h1 + h2 + h3;
            unsigned pre = lsum;
            #pragma unroll
            for (int off = 1; off < 64; off <<= 1) {
                unsigned v = __shfl_up(pre, off, 64);
                if (tid >= off) pre += v;
            }
            unsigned acc = pre - lsum;
            if (acc < target) {
                unsigned b2 = 256;
                if      (acc + h0           >= target) b2 = tid*4;
                else if (acc + h0 + h1      >= target) b2 = tid*4+1;
                else if (acc + h0 + h1 + h2 >= target) b2 = tid*4+2;
                else if (acc + lsum         >= target) b2 = tid*4+3;
                if (b2 < 256) sel_thr = (B << 8) | b2;
            }
        }
        __syncthreads();
        const unsigned thr = sel_thr;
        for (int i = tid; i < (int)M; i += NTHR) {
            unsigned long long key = keybuf[i];
            if (((unsigned)(key >> sh) & 0xFFFFu) <= thr) {
                unsigned pos = atomicAdd(&sel_cnt, 1u);
                if (pos < 512) sortbuf[pos] = key;
            }
        }
        __syncthreads();
    } else {
        for (int i = tid; i < (int)M; i += NTHR) sortbuf[i] = keybuf[i];
        if (tid == 0) sel_cnt = M;
        __syncthreads();
    }

    // ---- sort top candidates (ascending key == score desc, idx asc) --------
    const unsigned C2 = sel_cnt;
    unsigned long long* sorted;
    if (C2 <= 256) {
        unsigned long long v = ~0ULL;
        if (tid < 256) {
            v = (tid < (int)C2) ? sortbuf[tid] : ~0ULL;
            #pragma unroll
            for (unsigned k = 2; k <= 64; k <<= 1) {
                for (unsigned j = k >> 1; j > 0; j >>= 1) {
                    unsigned long long o = shfl_xor_u64(v, (int)j);
                    bool tm = (((tid & k) == 0) == ((tid & j) == 0));
                    v = tm ? (v < o ? v : o) : (v > o ? v : o);
                }
            }
        }
        __syncthreads();
        if (tid < 256) sortbuf[tid] = v;
        __syncthreads();
        if (tid < 256) {           // k = 128: j = 64 via LDS, then shfl
            unsigned long long o = sortbuf[tid ^ 64];
            bool tm = (((tid & 128) == 0) == ((tid & 64) == 0));
            v = tm ? (v < o ? v : o) : (v > o ? v : o);
            #pragma unroll
            for (unsigned j = 32; j > 0; j >>= 1) {
                unsigned long long o2 = shfl_xor_u64(v, (int)j);
                bool t2 = (((tid & 128) == 0) == ((tid & j) == 0));
                v = t2 ? (v < o2 ? v : o2) : (v > o2 ? v : o2);
            }
        }
        __syncthreads();
        if (tid < 256) sortbuf[tid] = v;
        __syncthreads();
        if (tid < 256) {           // k = 256: j = 128 via LDS
            unsigned long long o = sortbuf[tid ^ 128];
            bool tm = ((tid & 128) == 0);
            v = tm ? (v < o ? v : o) : (v > o ? v : o);
        }
        __syncthreads();
        if (tid < 256) sortbuf[tid] = v;
        __syncthreads();
        if (tid < 256) {           // k = 256: j = 64 via LDS, then shfl
            unsigned long long o = sortbuf[tid ^ 64];
            bool tm = ((tid & 64) == 0);
            v = tm ? (v < o ? v : o) : (v > o ? v : o);
            #pragma unroll
            for (unsigned j = 32; j > 0; j >>= 1) {
                unsigned long long o2 = shfl_xor_u64(v, (int)j);
                bool t2 = ((tid & j) == 0);
                v = t2 ? (v < o2 ? v : o2) : (v > o2 ? v : o2);
            }
        }
        __syncthreads();
        if (tid < 256) sortbuf[tid] = v;
        __syncthreads();
        sorted = sortbuf;
    } else if (C2 <= 512) {
        for (int i = (int)C2 + tid; i < 512; i += NTHR) sortbuf[i] = ~0ULL;
        __syncthreads();
        bitonic_sort(sortbuf, 512, tid);
        sorted = sortbuf;
    } else {                                   // adversarial tie storm
        for (int i = (int)M + tid; i < CAP; i += NTHR) keybuf[i] = ~0ULL;
        __syncthreads();
        bitonic_sort(keybuf, CAP, tid);
        sorted = keybuf;
    }

    // ---- decode top-200 ----------------------------------------------------
    if (tid < KPRE) {
        unsigned long long key = sorted[tid];
        if (key != ~0ULL) {
            unsigned n = (unsigned)key;
            unsigned v = ~(unsigned)(key >> 32);
            v = (v >> 31) ? (v ^ 0x80000000u) : ~v;
            float x  = __uint_as_float(v);
            float sc = 1.0f / (1.0f + expf(-x));
            const float* bp = pred + (size_t)b * NA * 7 + (size_t)n * 7;
            float d0 = bp[0] * 0.1f, d1 = bp[1] * 0.1f;
            float d2 = bp[2] * 0.2f, d3 = bp[3] * 0.2f;
            float cx, cy, aw, ah;
            anchor_of((int)n, cx, cy, aw, ah);
            float xx = d0 * aw + cx;
            float yy = d1 * ah + cy;
            float ww = expf(d2) * aw;
            float hh = expf(d3) * ah;
            boxes[tid]    = make_float4(xx - ww * 0.5f, yy - hh * 0.5f,
                                        xx + ww * 0.5f, yy + hh * 0.5f);
            scores_s[tid] = sc;
        } else {
            boxes[tid]    = make_float4(0, 0, 0, 0);
            scores_s[tid] = -1.0f;
        }
    } else if (tid < 256) {
        scores_s[tid] = -1.0f;
    }
    __syncthreads();

    // ---- pairwise IoU bitmasks: (row, chunk) 2D decomposition --------------
    {
        const int row = tid & 255;
        const int cb  = tid >> 8;
        unsigned long long m = 0ULL;
        if (row < KPRE) {
            const int lo = cb * 64;
            const int hi = min(lo + 64, KPRE);
            float4 bi = boxes[row];
            float areai = (bi.z - bi.x) * (bi.w - bi.y);
            for (int j = max(row + 1, lo); j < hi; ++j) {
                float4 bj = boxes[j];
                float x1 = fmaxf(bi.x, bj.x), y1 = fmaxf(bi.y, bj.y);
                float x2 = fminf(bi.z, bj.z), y2 = fminf(bi.w, bj.w);
                float iw = fmaxf(x2 - x1, 0.0f), ih = fmaxf(y2 - y1, 0.0f);
                float inter = iw * ih;
                float areaj = (bj.z - bj.x) * (bj.w - bj.y);
                float uni   = fmaxf(areai + areaj - inter, 1e-8f);
                if (inter / uni > 0.5f) m |= 1ULL << (j - lo);
            }
        }
        mask[row][cb] = m;
    }
    __syncthreads();

    // ---- wave-parallel greedy sweep (wave 0), exact sequential semantics ---
    if (tid < 64) {
        unsigned long long keep[4];
        #pragma unroll
        for (int cb = 0; cb < 4; ++cb)
            keep[cb] = __ballot(scores_s[cb * 64 + lane] >= 0.05f);

        #pragma unroll
        for (int cb = 0; cb < 4; ++cb) {
            unsigned long long mw_self = mask[cb * 64 + lane][cb];
            unsigned long long kw   = keep[cb];
            unsigned long long work = kw & __ballot(mw_self != 0ULL);
            while (work) {                       // uniform loop
                int t = __ffsll(work) - 1;
                work &= work - 1;
                if ((kw >> t) & 1ULL) {
                    unsigned long long m = __shfl(mw_self, t, 64);
                    kw   &= ~m;
                    work &= ~m;
                }
            }
            keep[cb] = kw;
            #pragma unroll
            for (int w = cb + 1; w < 4; ++w) {
                unsigned long long myw = mask[cb * 64 + lane][w];
                if ((__ballot(myw != 0ULL) & kw) == 0ULL) continue;
                unsigned long long contrib = ((kw >> lane) & 1ULL) ? myw : 0ULL;
                #pragma unroll
                for (int off = 1; off < 64; off <<= 1)
                    contrib |= __shfl_xor(contrib, off, 64);
                keep[w] &= ~contrib;
            }
        }

        if (lane == 0) {
            int k = 0;
            #pragma unroll
            for (int cb = 0; cb < 4; ++cb) {
                unsigned long long kw = keep[cb];
                while (kw && k < 10) {
                    int t = __ffsll(kw) - 1; kw &= kw - 1;
                    int i = cb * 64 + t;
                    s10[blk * 10 + k] = scores_s[i];
                    b10[blk * 10 + k] = boxes[i];
                    ++k;
                }
            }
            #pragma unroll
            for (int cb = 0; cb < 4; ++cb) {
                unsigned long long nk = ~keep[cb];
                if (cb == 3) nk &= 0xFFULL;          // i < 200
                while (nk && k < 10) {
                    int t = __ffsll(nk) - 1; nk &= nk - 1;
                    int i = cb * 64 + t;
                    s10[blk * 10 + k] = -1.0f;
                    b10[blk * 10 + k] = boxes[i];
                    ++k;
                }
            }
            __threadfence();
            __hip_atomic_fetch_add(&done[b], 1u, __ATOMIC_RELEASE,
                                   __HIP_MEMORY_SCOPE_AGENT);
        }
    }
}

// ---------------- launch ----------------------------------------------------
extern "C" void kernel_launch(void* const* d_in, const int* in_sizes, int n_in,
                              void* d_out, int out_size, void* d_ws, size_t ws_size,
                              hipStream_t stream) {
    const float* pred = (const float*)d_in[1];   // d_in[0] = images (shape only)

    char* ws = (char*)d_ws;
    unsigned*            sdone = (unsigned*)           (ws + WS_SDONE);
    unsigned*            done  = (unsigned*)           (ws + WS_DONE);
    unsigned*            gcnt  = (unsigned*)           (ws + WS_GCNT);
    float*               s10   = (float*)              (ws + WS_S10);
    float4*              b10   = (float4*)             (ws + WS_B10);
    unsigned long long*  keys  = (unsigned long long*) (ws + WS_KEYS);

    hipMemsetAsync(ws, 0, 640, stream);          // sdone + done + gcnt
    fused_kernel<<<128, NTHR, 0, stream>>>(pred, sdone, gcnt, keys,
                                           s10, b10, done, (float*)d_out);
}

// Round 14
// 57.322 us; speedup vs baseline: 6.0395x; 1.7143x over previous
//
#include <hip/hip_runtime.h>
#include <math.h>

#define NA      49104
#define NB      32
#define KPRE    200
#define CAP     2048
#define NSLICE  64
#define NQ4     85932           // NA*7/4 float4 per batch row (exact)
#define PERQ    1344            // NSLICE*PERQ >= NQ4; PERQ % 448 == 0, % 7 == 0
#define STHR    448             // scan threads: stride % 7 == 0
#define TAU     2.0f            // static candidate threshold (fallback guards it)
#define NBINS   512             // fallback histogram bins
#define SLOTCAP 64              // per-(b,c,slice) fixed key slots
#define NTHR    1024            // nms/merge block width (4 waves/SIMD)

// ---- workspace layout (bytes) ----------------------------------------------
#define WS_CNT   0                                   // 96*64*4   = 24576
#define WS_KEYS  24576                               // 96*4096*8 = 3145728
#define WS_S10   (WS_KEYS + 96*NSLICE*SLOTCAP*8)     // 96*10*4   = 3840
#define WS_B10   (WS_S10 + 96*10*4)                  // 96*10*16  = 15360
#define WS_DONE  (WS_B10 + 96*10*16)                 // 32*4

// ---------------- anchor generation (matches numpy reference) ---------------
__device__ __forceinline__ void anchor_of(int idx, float& cx, float& cy,
                                          float& aw, float& ah) {
    int l, r;
    if (idx < 36864)      { l = 0; r = idx; }
    else if (idx < 46080) { l = 1; r = idx - 36864; }
    else if (idx < 48384) { l = 2; r = idx - 46080; }
    else if (idx < 48960) { l = 3; r = idx - 48384; }
    else                  { l = 4; r = idx - 48960; }
    const int   fss[5]     = {64, 32, 16, 8, 4};
    const int   strides[5] = {8, 16, 32, 64, 128};
    const double areas[5]  = {1024.0, 23104.0, 73984.0, 153664.0, 262144.0};
    int a    = r % 9;
    int cell = r / 9;
    int fs   = fss[l];
    int jx   = cell % fs;
    int iy   = cell / fs;
    cx = ((float)jx + 0.5f) * (float)strides[l];
    cy = ((float)iy + 0.5f) * (float)strides[l];
    int ri = a / 3, si = a % 3;
    double ratio = (ri == 0) ? 0.5 : ((ri == 1) ? 1.0 : 2.0);
    double h = sqrt(areas[l] / ratio);
    double w = areas[l] / h;
    double s = (si == 0) ? 1.0
             : ((si == 1) ? 1.2599210498948732    // 2^(1/3)
                          : 1.5874010519681994);  // 2^(2/3)
    aw = (float)(s * w);
    ah = (float)(s * h);
}

__device__ __forceinline__ int bin_of(float x) {
    int bin = (int)floorf((x + 8.0f) * 32.0f);
    return min(max(bin, 0), NBINS - 1);
}

// order-preserving float->uint map (ascending uint == ascending float)
__device__ __forceinline__ unsigned omap(float x) {
    unsigned u = __float_as_uint(x);
    return u ^ ((u >> 31) ? 0xFFFFFFFFu : 0x80000000u);
}

__device__ __forceinline__ unsigned long long shfl_xor_u64(unsigned long long v,
                                                           int m) {
    unsigned lo = (unsigned)v, hi = (unsigned)(v >> 32);
    lo = __shfl_xor(lo, m, 64);
    hi = __shfl_xor(hi, m, 64);
    return ((unsigned long long)hi << 32) | lo;
}

// ---------------- kernel 1: single pass -> fixed-slot candidates ------------
__global__ __launch_bounds__(STHR) void scan_kernel(
        const float* __restrict__ pred, unsigned* __restrict__ cnts,
        unsigned long long* __restrict__ keys, unsigned* __restrict__ done) {
    const int blk = blockIdx.x;            // 32*64
    const int b   = blk >> 6;
    const int sl  = blk & 63;
    const int tid = threadIdx.x;

    __shared__ unsigned long long stage[3][SLOTCAP];
    __shared__ unsigned scnt[3];
    if (tid < 3) scnt[tid] = 0u;
    __syncthreads();

    // field pattern is iteration-invariant: q % 7 == tid % 7
    const int p = tid % 7;
    int cls[4];
    #pragma unroll
    for (int j = 0; j < 4; ++j) {
        int f = (4 * p + j) % 7;
        cls[j] = (f >= 4) ? (f - 4) : -1;
    }

    const float4* row = (const float4*)(pred + (size_t)b * NA * 7);
    const int q0 = sl * PERQ + tid;
    const int q1 = q0 + STHR, q2 = q1 + STHR;
    float4 v0, v1, v2;                     // hoisted independent loads (MLP)
    bool g0 = q0 < NQ4, g1 = q1 < NQ4, g2 = q2 < NQ4;
    if (g0) v0 = row[q0];
    if (g1) v1 = row[q1];
    if (g2) v2 = row[q2];

    #pragma unroll
    for (int it = 0; it < 3; ++it) {
        bool   g = (it == 0) ? g0 : (it == 1) ? g1 : g2;
        float4 v = (it == 0) ? v0 : (it == 1) ? v1 : v2;
        int    q = (it == 0) ? q0 : (it == 1) ? q1 : q2;
        if (!g) continue;
        float vv[4] = {v.x, v.y, v.z, v.w};
        #pragma unroll
        for (int j = 0; j < 4; ++j) {
            if (cls[j] >= 0 && vv[j] >= TAU) {
                int e = (q << 2) + j;
                int n = e / 7;
                unsigned u = __float_as_uint(vv[j]) | 0x80000000u; // x > 0
                unsigned long long key =
                    ((unsigned long long)(~u) << 32) | (unsigned)n;
                int c = cls[j];
                unsigned pos = atomicAdd(&scnt[c], 1u);
                if (pos < SLOTCAP) stage[c][pos] = key;
                // overflow: dropped here; count > SLOTCAP forces exact fallback
            }
        }
    }
    __syncthreads();

    if (tid < 3) cnts[(b * 3 + tid) * NSLICE + sl] = scnt[tid];
    if (tid == 3 && sl == 0) done[b] = 0u;   // ticket reset (pre-NMS, per call)

    #pragma unroll
    for (int c = 0; c < 3; ++c) {
        unsigned n = min(scnt[c], (unsigned)SLOTCAP);
        unsigned long long* dst =
            keys + ((size_t)(b * 3 + c) * NSLICE + sl) * SLOTCAP;
        for (unsigned i = tid; i < n; i += STHR) dst[i] = stage[c][i];
    }
}

// ---------------- in-LDS bitonic sort (ascending), NTHR threads -------------
__device__ __forceinline__ void bitonic_sort(unsigned long long* buf, unsigned P,
                                             int tid) {
    for (unsigned k = 2; k <= P; k <<= 1) {
        for (unsigned j = k >> 1; j > 0; j >>= 1) {
            for (unsigned i = tid; i < P; i += NTHR) {
                unsigned ixj = i ^ j;
                if (ixj > i) {
                    bool up = ((i & k) == 0);
                    unsigned long long a = buf[i], bb = buf[ixj];
                    if ((a > bb) == up) { buf[i] = bb; buf[ixj] = a; }
                }
            }
            __syncthreads();
        }
    }
}

// ---------------- kernel 2: NMS (96 blocks) + merge (32 blocks) -------------
__global__ __launch_bounds__(NTHR) void nms_merge_kernel(
        const float* __restrict__ pred, const unsigned* __restrict__ cnts,
        const unsigned long long* __restrict__ gkeys,
        float* __restrict__ s10, float4* __restrict__ b10,
        unsigned* __restrict__ done, float* __restrict__ out) {
    const int blk = blockIdx.x;            // 0..95 NMS, 96..127 merge
    const int tid = threadIdx.x;

    if (blk >= 96) {
        // ================= merge role: wait for batch's 3 classes ===========
        const int b = blk - 96;
        if (tid == 0) {
            while (__hip_atomic_load(&done[b], __ATOMIC_ACQUIRE,
                                     __HIP_MEMORY_SCOPE_AGENT) < 3u)
                __builtin_amdgcn_s_sleep(8);
        }
        __syncthreads();
        __threadfence();                   // make peers' s10/b10 visible

        if (tid < 64) {
            float s = (tid < 30) ? s10[b * 30 + tid] : -2.0f;
            float* ob = out + b * 40;
            float* os = out + 1280 + b * 10;
            float* oc = out + 1600 + b * 10;
            float* ov = out + 1920 + b;
            int valid = 0;
            for (int k = 0; k < 10; ++k) {
                unsigned u = __float_as_uint(s);
                unsigned o = (u >> 31) ? ~u : (u | 0x80000000u);
                unsigned long long key =
                    ((unsigned long long)o << 6) | (unsigned)(63 - tid);
                #pragma unroll
                for (int off = 1; off < 64; off <<= 1) {
                    unsigned long long k2 = __shfl_xor(key, off, 64);
                    key = (k2 > key) ? k2 : key;
                }
                int t = 63 - (int)(key & 63ULL);
                float best = __shfl(s, t, 64);
                bool v = best > 0.0f;
                if (tid == t) {
                    float4 bb = v ? b10[b * 30 + t] : make_float4(0, 0, 0, 0);
                    ob[k * 4 + 0] = bb.x; ob[k * 4 + 1] = bb.y;
                    ob[k * 4 + 2] = bb.z; ob[k * 4 + 3] = bb.w;
                    os[k] = v ? best : 0.0f;
                    oc[k] = v ? (float)(t / 10) : 0.0f;
                    s = -2.0f;
                }
                valid += v ? 1 : 0;
            }
            if (tid == 0) ov[0] = (float)valid;
        }
        return;
    }

    // ==================== class-NMS role (blk = b*3 + c) =====================
    const int b = blk / 3;
    const int c = blk % 3;

    __shared__ unsigned long long keybuf[CAP];
    __shared__ unsigned long long sortbuf[512];
    __shared__ float4 boxes[KPRE];
    __shared__ float  scores_s[256];
    __shared__ unsigned long long mask[256][4];
    __shared__ unsigned hist[256];
    __shared__ unsigned hist512[NBINS];
    __shared__ unsigned Lb[NSLICE], Bb[NSLICE];
    __shared__ unsigned sMn[16], sMx[16];
    __shared__ unsigned sel_thr, sel_cnt, s_prefB, s_cumB, s_M, s_sh, s_common;
    __shared__ int sT;

    if (tid < 256) hist[tid] = 0u;
    if (tid == 0) sel_cnt = 0u;

    // ---- slice-count prefix (wave 0) ---------------------------------------
    if (tid < 64) {
        unsigned L  = cnts[blk * NSLICE + tid];
        unsigned Lc = min(L, (unsigned)SLOTCAP);
        unsigned pre = Lc;
        #pragma unroll
        for (int off = 1; off < 64; off <<= 1) {
            unsigned v = __shfl_up(pre, off, 64);
            if (tid >= off) pre += v;
        }
        Lb[tid] = Lc;
        Bb[tid] = pre - Lc;
        unsigned long long ob = __ballot(L > SLOTCAP);
        if (tid == 63) s_M = pre;
        if (tid == 0)  s_common = (ob == 0ULL) ? 1u : 0u;
    }
    __syncthreads();

    const unsigned M0 = s_M;
    const bool common = s_common && M0 >= KPRE && M0 <= CAP;

    if (common) {
        // gather fixed slots -> compact keybuf ([0,M) fully written, no init)
        const unsigned long long* src = gkeys + (size_t)blk * NSLICE * SLOTCAP;
        #pragma unroll
        for (int u = 0; u < NSLICE * SLOTCAP / NTHR; ++u) {
            int i = u * NTHR + tid;
            int sl = i >> 6, k = i & (SLOTCAP - 1);
            if ((unsigned)k < Lb[sl]) keybuf[Bb[sl] + k] = src[i];
        }
    } else {
        // ---- exact in-block fallback: histogram threshold + recollect ------
        for (int i = tid; i < NBINS; i += NTHR) hist512[i] = 0u;
        if (tid == 0) s_M = 0u;
        __syncthreads();
        const float* base = pred + (size_t)b * NA * 7 + 4 + c;
        for (int n = tid; n < NA; n += NTHR)
            atomicAdd(&hist512[bin_of(base[(size_t)n * 7])], 1u);
        __syncthreads();
        if (tid < 64) {                                 // wave-0 suffix scan
            unsigned h[8]; unsigned lsum = 0;
            #pragma unroll
            for (int k = 0; k < 8; ++k) { h[k] = hist512[tid*8+k]; lsum += h[k]; }
            unsigned suf = lsum;
            #pragma unroll
            for (int off = 1; off < 64; off <<= 1) {
                unsigned v = __shfl_down(suf, off, 64);
                if (tid < 64 - off) suf += v;
            }
            unsigned acc = suf - lsum;                  // bins above my range
            #pragma unroll
            for (int k = 7; k >= 0; --k) {
                unsigned na = acc + h[k];
                if (na >= KPRE && acc < KPRE) sT = max(tid*8 + k - 1, 0);
                acc = na;
            }
        }
        __syncthreads();
        const int T = sT;
        for (int n = tid; n < NA; n += NTHR) {
            float x = base[(size_t)n * 7];
            if (bin_of(x) >= T) {
                unsigned long long key =
                    ((unsigned long long)(~omap(x)) << 32) | (unsigned)n;
                unsigned pos = atomicAdd(&s_M, 1u);
                if (pos < CAP) keybuf[pos] = key;
            }
        }
    }
    __syncthreads();
    const unsigned M = min(s_M, (unsigned)CAP);

    // ---- exact rank-KPRE selection: adaptive two-level digit hist ----------
    if (M > KPRE) {
        {   // top-byte uniformity probe
            unsigned mn = 0xFFu, mx = 0u;
            for (int i = tid; i < (int)M; i += NTHR) {
                unsigned h = (unsigned)(keybuf[i] >> 56);
                mn = min(mn, h); mx = max(mx, h);
            }
            #pragma unroll
            for (int off = 1; off < 64; off <<= 1) {
                mn = min(mn, (unsigned)__shfl_xor((int)mn, off, 64));
                mx = max(mx, (unsigned)__shfl_xor((int)mx, off, 64));
            }
            if ((tid & 63) == 0) { sMn[tid >> 6] = mn; sMx[tid >> 6] = mx; }
        }
        __syncthreads();
        if (tid == 0) {
            unsigned mn = 0xFFu, mx = 0u;
            #pragma unroll
            for (int w = 0; w < NTHR / 64; ++w) {
                mn = min(mn, sMn[w]); mx = max(mx, sMx[w]);
            }
            s_sh = (mn == mx) ? 40u : 48u;
        }
        __syncthreads();
        const unsigned sh = s_sh;

        for (int i = tid; i < (int)M; i += NTHR)
            atomicAdd(&hist[(unsigned)(keybuf[i] >> (sh + 8)) & 0xFFu], 1u);
        __syncthreads();
        if (tid < 64) {                                 // wave-0 prefix scan
            unsigned h0 = hist[tid*4],   h1 = hist[tid*4+1];
            unsigned h2 = hist[tid*4+2], h3 = hist[tid*4+3];
            unsigned lsum = h0 + h1 + h2 + h3;
            unsigned pre = lsum;
            #pragma unroll
            for (int off = 1; off < 64; off <<= 1) {
                unsigned v = __shfl_up(pre, off, 64);
                if (tid >= off) pre += v;
            }
            unsigned acc = pre - lsum;                  // bins below my range
            if (acc < KPRE) {
                if      (acc + h0            >= KPRE) { s_prefB = tid*4;   s_cumB = acc; }
                else if (acc + h0 + h1       >= KPRE) { s_prefB = tid*4+1; s_cumB = acc+h0; }
                else if (acc + h0 + h1 + h2  >= KPRE) { s_prefB = tid*4+2; s_cumB = acc+h0+h1; }
                else if (acc + lsum          >= KPRE) { s_prefB = tid*4+3; s_cumB = acc+h0+h1+h2; }
            }
        }
        __syncthreads();
        const unsigned B = s_prefB, before = s_cumB;
        if (tid < 256) hist[tid] = 0u;
        __syncthreads();
        for (int i = tid; i < (int)M; i += NTHR) {
            unsigned long long key = keybuf[i];
            if (((unsigned)(key >> (sh + 8)) & 0xFFu) == B)
                atomicAdd(&hist[(unsigned)(key >> sh) & 0xFFu], 1u);
        }
        __syncthreads();
        if (tid < 64) {
            const unsigned target = KPRE - before;      // >= 1
            unsigned h0 = hist[tid*4],   h1 = hist[tid*4+1];
            unsigned h2 = hist[tid*4+2], h3 = hist[tid*4+3];
            unsigned lsum = h0 + h1 + h2 + h3;
            unsigned pre = lsum;
            #pragma unroll
            for (int off = 1; off < 64; off <<= 1) {
                unsigned v = __shfl_up(pre, off, 64);
                if (tid >= off) pre += v;
            }
            unsigned acc = pre - lsum;
            if (acc < target) {
                unsigned b2 = 256;
                if      (acc + h0           >= target) b2 = tid*4;
                else if (acc + h0 + h1      >= target) b2 = tid*4+1;
                else if (acc + h0 + h1 + h2 >= target) b2 = tid*4+2;
                else if (acc + lsum         >= target) b2 = tid*4+3;
                if (b2 < 256) sel_thr = (B << 8) | b2;
            }
        }
        __syncthreads();
        const unsigned thr = sel_thr;
        for (int i = tid; i < (int)M; i += NTHR) {
            unsigned long long key = keybuf[i];
            if (((unsigned)(key >> sh) & 0xFFFFu) <= thr) {
                unsigned pos = atomicAdd(&sel_cnt, 1u);
                if (pos < 512) sortbuf[pos] = key;
            }
        }
        __syncthreads();
    } else {
        for (int i = tid; i < (int)M; i += NTHR) sortbuf[i] = keybuf[i];
        if (tid == 0) sel_cnt = M;
        __syncthreads();
    }

    // ---- sort top candidates (ascending key == score desc, idx asc) --------
    const unsigned C2 = sel_cnt;
    unsigned long long* sorted;
    if (C2 <= 256) {
        // register/shfl bitonic-256 on waves 0-3 (wave-uniform guards;
        // barriers hoisted block-wide)
        unsigned long long v = ~0ULL;
        if (tid < 256) {
            v = (tid < (int)C2) ? sortbuf[tid] : ~0ULL;
            #pragma unroll
            for (unsigned k = 2; k <= 64; k <<= 1) {
                for (unsigned j = k >> 1; j > 0; j >>= 1) {
                    unsigned long long o = shfl_xor_u64(v, (int)j);
                    bool tm = (((tid & k) == 0) == ((tid & j) == 0));
                    v = tm ? (v < o ? v : o) : (v > o ? v : o);
                }
            }
        }
        __syncthreads();
        if (tid < 256) sortbuf[tid] = v;
        __syncthreads();
        if (tid < 256) {           // k = 128: j = 64 via LDS, then shfl
            unsigned long long o = sortbuf[tid ^ 64];
            bool tm = (((tid & 128) == 0) == ((tid & 64) == 0));
            v = tm ? (v < o ? v : o) : (v > o ? v : o);
            #pragma unroll
            for (unsigned j = 32; j > 0; j >>= 1) {
                unsigned long long o2 = shfl_xor_u64(v, (int)j);
                bool t2 = (((tid & 128) == 0) == ((tid & j) == 0));
                v = t2 ? (v < o2 ? v : o2) : (v > o2 ? v : o2);
            }
        }
        __syncthreads();
        if (tid < 256) sortbuf[tid] = v;
        __syncthreads();
        if (tid < 256) {           // k = 256: j = 128 via LDS
            unsigned long long o = sortbuf[tid ^ 128];
            bool tm = ((tid & 128) == 0);
            v = tm ? (v < o ? v : o) : (v > o ? v : o);
        }
        __syncthreads();
        if (tid < 256) sortbuf[tid] = v;
        __syncthreads();
        if (tid < 256) {           // k = 256: j = 64 via LDS, then shfl
            unsigned long long o = sortbuf[tid ^ 64];
            bool tm = ((tid & 64) == 0);
            v = tm ? (v < o ? v : o) : (v > o ? v : o);
            #pragma unroll
            for (unsigned j = 32; j > 0; j >>= 1) {
                unsigned long long o2 = shfl_xor_u64(v, (int)j);
                bool t2 = ((tid & j) == 0);
                v = t2 ? (v < o2 ? v : o2) : (v > o2 ? v : o2);
            }
        }
        __syncthreads();
        if (tid < 256) sortbuf[tid] = v;
        __syncthreads();
        sorted = sortbuf;
    } else if (C2 <= 512) {
        for (int i = (int)C2 + tid; i < 512; i += NTHR) sortbuf[i] = ~0ULL;
        __syncthreads();
        bitonic_sort(sortbuf, 512, tid);
        sorted = sortbuf;
    } else {                                   // adversarial tie storm
        for (int i = (int)M + tid; i < CAP; i += NTHR) keybuf[i] = ~0ULL;
        __syncthreads();
        bitonic_sort(keybuf, CAP, tid);
        sorted = keybuf;
    }

    // ---- decode top-200 ----------------------------------------------------
    if (tid < KPRE) {
        unsigned long long key = sorted[tid];
        if (key != ~0ULL) {
            unsigned n = (unsigned)key;
            unsigned v = ~(unsigned)(key >> 32);
            v = (v >> 31) ? (v ^ 0x80000000u) : ~v;
            float x  = __uint_as_float(v);
            float sc = 1.0f / (1.0f + expf(-x));
            const float* bp = pred + (size_t)b * NA * 7 + (size_t)n * 7;
            float d0 = bp[0] * 0.1f, d1 = bp[1] * 0.1f;
            float d2 = bp[2] * 0.2f, d3 = bp[3] * 0.2f;
            float cx, cy, aw, ah;
            anchor_of((int)n, cx, cy, aw, ah);
            float xx = d0 * aw + cx;
            float yy = d1 * ah + cy;
            float ww = expf(d2) * aw;
            float hh = expf(d3) * ah;
            boxes[tid]    = make_float4(xx - ww * 0.5f, yy - hh * 0.5f,
                                        xx + ww * 0.5f, yy + hh * 0.5f);
            scores_s[tid] = sc;
        } else {
            boxes[tid]    = make_float4(0, 0, 0, 0);
            scores_s[tid] = -1.0f;
        }
    } else if (tid < 256) {
        scores_s[tid] = -1.0f;
    }
    __syncthreads();

    // ---- pairwise IoU bitmasks: (row, chunk) 2D decomposition --------------
    // thread (row = tid&255, cb = tid>>8) computes mask[row][cb]; inner loop
    // <= 64 iterations (4x shorter critical path than row-per-thread).
    {
        const int row = tid & 255;
        const int cb  = tid >> 8;
        unsigned long long m = 0ULL;
        if (row < KPRE) {
            const int lo = cb * 64;
            const int hi = min(lo + 64, KPRE);
            float4 bi = boxes[row];
            float areai = (bi.z - bi.x) * (bi.w - bi.y);
            for (int j = max(row + 1, lo); j < hi; ++j) {
                float4 bj = boxes[j];
                float x1 = fmaxf(bi.x, bj.x), y1 = fmaxf(bi.y, bj.y);
                float x2 = fminf(bi.z, bj.z), y2 = fminf(bi.w, bj.w);
                float iw = fmaxf(x2 - x1, 0.0f), ih = fmaxf(y2 - y1, 0.0f);
                float inter = iw * ih;
                float areaj = (bj.z - bj.x) * (bj.w - bj.y);
                float uni   = fmaxf(areai + areaj - inter, 1e-8f);
                if (inter / uni > 0.5f) m |= 1ULL << (j - lo);
            }
        }
        mask[row][cb] = m;
    }
    __syncthreads();

    // ---- wave-parallel greedy sweep (wave 0), exact sequential semantics ---
    if (tid < 64) {
        const int lane = tid;
        unsigned long long keep[4];
        #pragma unroll
        for (int cb = 0; cb < 4; ++cb)
            keep[cb] = __ballot(scores_s[cb * 64 + lane] >= 0.05f);

        #pragma unroll
        for (int cb = 0; cb < 4; ++cb) {
            unsigned long long mw_self = mask[cb * 64 + lane][cb];
            unsigned long long kw   = keep[cb];
            // empty-mask rows can't suppress anyone -> skip them
            unsigned long long work = kw & __ballot(mw_self != 0ULL);
            while (work) {                       // uniform loop
                int t = __ffsll(work) - 1;
                work &= work - 1;
                if ((kw >> t) & 1ULL) {          // alive when its turn comes
                    unsigned long long m = __shfl(mw_self, t, 64);
                    kw   &= ~m;
                    work &= ~m;
                }
            }
            keep[cb] = kw;
            #pragma unroll
            for (int w = cb + 1; w < 4; ++w) {
                unsigned long long myw = mask[cb * 64 + lane][w];
                if ((__ballot(myw != 0ULL) & kw) == 0ULL) continue;
                unsigned long long contrib = ((kw >> lane) & 1ULL) ? myw : 0ULL;
                #pragma unroll
                for (int off = 1; off < 64; off <<= 1)
                    contrib |= __shfl_xor(contrib, off, 64);
                keep[w] &= ~contrib;
            }
        }

        if (lane == 0) {
            int k = 0;
            #pragma unroll
            for (int cb = 0; cb < 4; ++cb) {
                unsigned long long kw = keep[cb];
                while (kw && k < 10) {
                    int t = __ffsll(kw) - 1; kw &= kw - 1;
                    int i = cb * 64 + t;
                    s10[blk * 10 + k] = scores_s[i];
                    b10[blk * 10 + k] = boxes[i];
                    ++k;
                }
            }
            #pragma unroll
            for (int cb = 0; cb < 4; ++cb) {
                unsigned long long nk = ~keep[cb];
                if (cb == 3) nk &= 0xFFULL;          // i < 200
                while (nk && k < 10) {
                    int t = __ffsll(nk) - 1; nk &= nk - 1;
                    int i = cb * 64 + t;
                    s10[blk * 10 + k] = -1.0f;
                    b10[blk * 10 + k] = boxes[i];
                    ++k;
                }
            }
            // release this class's results to the merge block
            __threadfence();
            __hip_atomic_fetch_add(&done[b], 1u, __ATOMIC_RELEASE,
                                   __HIP_MEMORY_SCOPE_AGENT);
        }
    }
}

// ---------------- launch ----------------------------------------------------
extern "C" void kernel_launch(void* const* d_in, const int* in_sizes, int n_in,
                              void* d_out, int out_size, void* d_ws, size_t ws_size,
                              hipStream_t stream) {
    const float* pred = (const float*)d_in[1];   // d_in[0] = images (shape only)

    char* ws = (char*)d_ws;
    unsigned*            cnts = (unsigned*)           (ws + WS_CNT);
    unsigned long long*  keys = (unsigned long long*) (ws + WS_KEYS);
    float*               s10  = (float*)              (ws + WS_S10);
    float4*              b10  = (float4*)             (ws + WS_B10);
    unsigned*            done = (unsigned*)           (ws + WS_DONE);

    scan_kernel     <<<NB * NSLICE, STHR, 0, stream>>>(pred, cnts, keys, done);
    nms_merge_kernel<<<128, NTHR, 0, stream>>>(pred, cnts, keys, s10, b10, done,
                                               (float*)d_out);
}

// Round 15
// 56.468 us; speedup vs baseline: 6.1309x; 1.0151x over previous
//
#include <hip/hip_runtime.h>
#include <math.h>

#define NA      49104
#define NB      32
#define KPRE    200
#define CAP     2048
#define NSLICE  64
#define NQ4     85932           // NA*7/4 float4 per batch row (exact)
#define PERQ    1344            // NSLICE*PERQ >= NQ4; PERQ % 448 == 0, % 7 == 0
#define STHR    448             // scan threads: stride % 7 == 0
#define TAU     2.0f            // static candidate threshold (fallback guards it)
#define NBINS   512             // fallback histogram bins
#define SLOTCAP 64              // per-(b,c,slice) fixed key slots
#define NTHR    1024            // nms/merge block width

// ---- workspace layout (bytes) ----------------------------------------------
#define WS_CNT   0                                   // 96*64*4   = 24576
#define WS_KEYS  24576                               // 96*4096*8 = 3145728
#define WS_S10   (WS_KEYS + 96*NSLICE*SLOTCAP*8)     // 96*10*4   = 3840
#define WS_B10   (WS_S10 + 96*10*4)                  // 96*10*16  = 15360
#define WS_DONE  (WS_B10 + 96*10*16)                 // 32*4

// ---------------- anchor generation (matches numpy reference) ---------------
__device__ __forceinline__ void anchor_of(int idx, float& cx, float& cy,
                                          float& aw, float& ah) {
    int l, r;
    if (idx < 36864)      { l = 0; r = idx; }
    else if (idx < 46080) { l = 1; r = idx - 36864; }
    else if (idx < 48384) { l = 2; r = idx - 46080; }
    else if (idx < 48960) { l = 3; r = idx - 48384; }
    else                  { l = 4; r = idx - 48960; }
    const int   fss[5]     = {64, 32, 16, 8, 4};
    const int   strides[5] = {8, 16, 32, 64, 128};
    const double areas[5]  = {1024.0, 23104.0, 73984.0, 153664.0, 262144.0};
    int a    = r % 9;
    int cell = r / 9;
    int fs   = fss[l];
    int jx   = cell % fs;
    int iy   = cell / fs;
    cx = ((float)jx + 0.5f) * (float)strides[l];
    cy = ((float)iy + 0.5f) * (float)strides[l];
    int ri = a / 3, si = a % 3;
    double ratio = (ri == 0) ? 0.5 : ((ri == 1) ? 1.0 : 2.0);
    double h = sqrt(areas[l] / ratio);
    double w = areas[l] / h;
    double s = (si == 0) ? 1.0
             : ((si == 1) ? 1.2599210498948732    // 2^(1/3)
                          : 1.5874010519681994);  // 2^(2/3)
    aw = (float)(s * w);
    ah = (float)(s * h);
}

__device__ __forceinline__ int bin_of(float x) {
    int bin = (int)floorf((x + 8.0f) * 32.0f);
    return min(max(bin, 0), NBINS - 1);
}

// order-preserving float->uint map (ascending uint == ascending float)
__device__ __forceinline__ unsigned omap(float x) {
    unsigned u = __float_as_uint(x);
    return u ^ ((u >> 31) ? 0xFFFFFFFFu : 0x80000000u);
}

__device__ __forceinline__ unsigned long long shfl_xor_u64(unsigned long long v,
                                                           int m) {
    unsigned lo = (unsigned)v, hi = (unsigned)(v >> 32);
    lo = __shfl_xor(lo, m, 64);
    hi = __shfl_xor(hi, m, 64);
    return ((unsigned long long)hi << 32) | lo;
}

// ---------------- kernel 1: single pass -> fixed-slot candidates ------------
__global__ __launch_bounds__(STHR) void scan_kernel(
        const float* __restrict__ pred, unsigned* __restrict__ cnts,
        unsigned long long* __restrict__ keys, unsigned* __restrict__ done) {
    const int blk = blockIdx.x;            // 32*64
    const int b   = blk >> 6;
    const int sl  = blk & 63;
    const int tid = threadIdx.x;

    __shared__ unsigned long long stage[3][SLOTCAP];
    __shared__ unsigned scnt[3];
    if (tid < 3) scnt[tid] = 0u;
    __syncthreads();

    // field pattern is iteration-invariant: q % 7 == tid % 7
    const int p = tid % 7;
    int cls[4];
    #pragma unroll
    for (int j = 0; j < 4; ++j) {
        int f = (4 * p + j) % 7;
        cls[j] = (f >= 4) ? (f - 4) : -1;
    }

    const float4* row = (const float4*)(pred + (size_t)b * NA * 7);
    const int q0 = sl * PERQ + tid;
    const int q1 = q0 + STHR, q2 = q1 + STHR;
    float4 v0, v1, v2;                     // hoisted independent loads (MLP)
    bool g0 = q0 < NQ4, g1 = q1 < NQ4, g2 = q2 < NQ4;
    if (g0) v0 = row[q0];
    if (g1) v1 = row[q1];
    if (g2) v2 = row[q2];

    #pragma unroll
    for (int it = 0; it < 3; ++it) {
        bool   g = (it == 0) ? g0 : (it == 1) ? g1 : g2;
        float4 v = (it == 0) ? v0 : (it == 1) ? v1 : v2;
        int    q = (it == 0) ? q0 : (it == 1) ? q1 : q2;
        if (!g) continue;
        float vv[4] = {v.x, v.y, v.z, v.w};
        #pragma unroll
        for (int j = 0; j < 4; ++j) {
            if (cls[j] >= 0 && vv[j] >= TAU) {
                int e = (q << 2) + j;
                int n = e / 7;
                unsigned u = __float_as_uint(vv[j]) | 0x80000000u; // x > 0
                unsigned long long key =
                    ((unsigned long long)(~u) << 32) | (unsigned)n;
                int c = cls[j];
                unsigned pos = atomicAdd(&scnt[c], 1u);
                if (pos < SLOTCAP) stage[c][pos] = key;
                // overflow: dropped here; count > SLOTCAP forces exact fallback
            }
        }
    }
    __syncthreads();

    if (tid < 3) cnts[(b * 3 + tid) * NSLICE + sl] = scnt[tid];
    if (tid == 3 && sl == 0) done[b] = 0u;   // ticket reset (pre-NMS, per call)

    #pragma unroll
    for (int c = 0; c < 3; ++c) {
        unsigned n = min(scnt[c], (unsigned)SLOTCAP);
        unsigned long long* dst =
            keys + ((size_t)(b * 3 + c) * NSLICE + sl) * SLOTCAP;
        for (unsigned i = tid; i < n; i += STHR) dst[i] = stage[c][i];
    }
}

// ---------------- in-LDS bitonic sort (ascending), NTHR threads -------------
__device__ __forceinline__ void bitonic_sort(unsigned long long* buf, unsigned P,
                                             int tid) {
    for (unsigned k = 2; k <= P; k <<= 1) {
        for (unsigned j = k >> 1; j > 0; j >>= 1) {
            for (unsigned i = tid; i < P; i += NTHR) {
                unsigned ixj = i ^ j;
                if (ixj > i) {
                    bool up = ((i & k) == 0);
                    unsigned long long a = buf[i], bb = buf[ixj];
                    if ((a > bb) == up) { buf[i] = bb; buf[ixj] = a; }
                }
            }
            __syncthreads();
        }
    }
}

// ---------------- kernel 2: NMS (96 blocks) + merge (32 blocks) -------------
__global__ __launch_bounds__(NTHR) void nms_merge_kernel(
        const float* __restrict__ pred, const unsigned* __restrict__ cnts,
        const unsigned long long* __restrict__ gkeys,
        float* __restrict__ s10, float4* __restrict__ b10,
        unsigned* __restrict__ done, float* __restrict__ out) {
    const int blk = blockIdx.x;            // 0..95 NMS, 96..127 merge
    const int tid = threadIdx.x;

    if (blk >= 96) {
        // ================= merge role: wait for batch's 3 classes ===========
        const int b = blk - 96;
        if (tid == 0) {
            while (__hip_atomic_load(&done[b], __ATOMIC_ACQUIRE,
                                     __HIP_MEMORY_SCOPE_AGENT) < 3u)
                __builtin_amdgcn_s_sleep(8);
        }
        __syncthreads();
        __threadfence();                   // make peers' s10/b10 visible

        if (tid < 64) {
            float s = (tid < 30) ? s10[b * 30 + tid] : -2.0f;
            float* ob = out + b * 40;
            float* os = out + 1280 + b * 10;
            float* oc = out + 1600 + b * 10;
            float* ov = out + 1920 + b;
            int valid = 0;
            for (int k = 0; k < 10; ++k) {
                unsigned u = __float_as_uint(s);
                unsigned o = (u >> 31) ? ~u : (u | 0x80000000u);
                unsigned long long key =
                    ((unsigned long long)o << 6) | (unsigned)(63 - tid);
                #pragma unroll
                for (int off = 1; off < 64; off <<= 1) {
                    unsigned long long k2 = __shfl_xor(key, off, 64);
                    key = (k2 > key) ? k2 : key;
                }
                int t = 63 - (int)(key & 63ULL);
                float best = __shfl(s, t, 64);
                bool v = best > 0.0f;
                if (tid == t) {
                    float4 bb = v ? b10[b * 30 + t] : make_float4(0, 0, 0, 0);
                    ob[k * 4 + 0] = bb.x; ob[k * 4 + 1] = bb.y;
                    ob[k * 4 + 2] = bb.z; ob[k * 4 + 3] = bb.w;
                    os[k] = v ? best : 0.0f;
                    oc[k] = v ? (float)(t / 10) : 0.0f;
                    s = -2.0f;
                }
                valid += v ? 1 : 0;
            }
            if (tid == 0) ov[0] = (float)valid;
        }
        return;
    }

    // ==================== class-NMS role (blk = b*3 + c) =====================
    const int b = blk / 3;
    const int c = blk % 3;
    const int lane = tid & 63;

    __shared__ unsigned long long keybuf[CAP];
    __shared__ unsigned long long sortbuf[512];
    __shared__ float4 boxes[KPRE];
    __shared__ float  scores_s[256];
    __shared__ unsigned long long mask[256][4];
    __shared__ unsigned hist[256];
    __shared__ unsigned hist2[256];
    __shared__ unsigned hist512[NBINS];
    __shared__ unsigned Lb[NSLICE], Bb[NSLICE];
    __shared__ unsigned sMn[16], sMx[16];
    __shared__ unsigned sel_thr, sel_cnt, s_prefB, s_cumB, s_M, s_sh, s_common;
    __shared__ int sT;

    if (tid < 256) { hist[tid] = 0u; hist2[tid] = 0u; }
    if (tid == 0) sel_cnt = 0u;

    // ---- slice-count prefix (wave 0) ---------------------------------------
    if (tid < 64) {
        unsigned L  = cnts[blk * NSLICE + tid];
        unsigned Lc = min(L, (unsigned)SLOTCAP);
        unsigned pre = Lc;
        #pragma unroll
        for (int off = 1; off < 64; off <<= 1) {
            unsigned v = __shfl_up(pre, off, 64);
            if (tid >= off) pre += v;
        }
        Lb[tid] = Lc;
        Bb[tid] = pre - Lc;
        unsigned long long ob = __ballot(L > SLOTCAP);
        if (tid == 63) s_M = pre;
        if (tid == 0)  s_common = (ob == 0ULL) ? 1u : 0u;
    }
    __syncthreads();

    const unsigned M0 = s_M;
    const bool common = s_common && M0 >= KPRE && M0 <= CAP;

    // top-byte min/max folded into key production (probe phase eliminated)
    unsigned tmn = 0xFFu, tmx = 0u;

    if (common) {
        // gather fixed slots -> compact keybuf ([0,M) fully written, no init)
        const unsigned long long* src = gkeys + (size_t)blk * NSLICE * SLOTCAP;
        #pragma unroll
        for (int u = 0; u < NSLICE * SLOTCAP / NTHR; ++u) {
            int i = u * NTHR + tid;
            int sl = i >> 6, k = i & (SLOTCAP - 1);
            if ((unsigned)k < Lb[sl]) {
                unsigned long long key = src[i];
                keybuf[Bb[sl] + k] = key;
                unsigned h = (unsigned)(key >> 56);
                tmn = min(tmn, h); tmx = max(tmx, h);
            }
        }
    } else {
        // ---- exact in-block fallback: histogram threshold + recollect ------
        for (int i = tid; i < NBINS; i += NTHR) hist512[i] = 0u;
        if (tid == 0) s_M = 0u;
        __syncthreads();
        const float* base = pred + (size_t)b * NA * 7 + 4 + c;
        for (int n = tid; n < NA; n += NTHR)
            atomicAdd(&hist512[bin_of(base[(size_t)n * 7])], 1u);
        __syncthreads();
        if (tid < 64) {                                 // wave-0 suffix scan
            unsigned h[8]; unsigned lsum = 0;
            #pragma unroll
            for (int k = 0; k < 8; ++k) { h[k] = hist512[tid*8+k]; lsum += h[k]; }
            unsigned suf = lsum;
            #pragma unroll
            for (int off = 1; off < 64; off <<= 1) {
                unsigned v = __shfl_down(suf, off, 64);
                if (tid < 64 - off) suf += v;
            }
            unsigned acc = suf - lsum;                  // bins above my range
            #pragma unroll
            for (int k = 7; k >= 0; --k) {
                unsigned na = acc + h[k];
                if (na >= KPRE && acc < KPRE) sT = max(tid*8 + k - 1, 0);
                acc = na;
            }
        }
        __syncthreads();
        const int T = sT;
        for (int n = tid; n < NA; n += NTHR) {
            float x = base[(size_t)n * 7];
            if (bin_of(x) >= T) {
                unsigned long long key =
                    ((unsigned long long)(~omap(x)) << 32) | (unsigned)n;
                unsigned pos = atomicAdd(&s_M, 1u);
                if (pos < CAP) keybuf[pos] = key;
                unsigned h = (unsigned)(key >> 56);     // superset-safe
                tmn = min(tmn, h); tmx = max(tmx, h);
            }
        }
    }
    // per-wave min/max reduce (no barrier needed within wave)
    #pragma unroll
    for (int off = 1; off < 64; off <<= 1) {
        tmn = min(tmn, (unsigned)__shfl_xor((int)tmn, off, 64));
        tmx = max(tmx, (unsigned)__shfl_xor((int)tmx, off, 64));
    }
    if (lane == 0) { sMn[tid >> 6] = tmn; sMx[tid >> 6] = tmx; }
    __syncthreads();
    const unsigned M = min(s_M, (unsigned)CAP);

    // ---- exact rank-KPRE selection: adaptive two-level digit hist ----------
    if (M > KPRE) {
        if (tid == 0) {
            unsigned mn = 0xFFu, mx = 0u;
            #pragma unroll
            for (int w = 0; w < NTHR / 64; ++w) {
                mn = min(mn, sMn[w]); mx = max(mx, sMx[w]);
            }
            s_sh = (mn == mx) ? 40u : 48u;   // uniform top byte -> finer digits
        }
        __syncthreads();
        const unsigned sh = s_sh;

        for (int i = tid; i < (int)M; i += NTHR)
            atomicAdd(&hist[(unsigned)(keybuf[i] >> (sh + 8)) & 0xFFu], 1u);
        __syncthreads();
        if (tid < 64) {                                 // wave-0 prefix scan
            unsigned h0 = hist[tid*4],   h1 = hist[tid*4+1];
            unsigned h2 = hist[tid*4+2], h3 = hist[tid*4+3];
            unsigned lsum = h0 + h1 + h2 + h3;
            unsigned pre = lsum;
            #pragma unroll
            for (int off = 1; off < 64; off <<= 1) {
                unsigned v = __shfl_up(pre, off, 64);
                if (tid >= off) pre += v;
            }
            unsigned acc = pre - lsum;                  // bins below my range
            if (acc < KPRE) {
                if      (acc + h0            >= KPRE) { s_prefB = tid*4;   s_cumB = acc; }
                else if (acc + h0 + h1       >= KPRE) { s_prefB = tid*4+1; s_cumB = acc+h0; }
                else if (acc + h0 + h1 + h2  >= KPRE) { s_prefB = tid*4+2; s_cumB = acc+h0+h1; }
                else if (acc + lsum          >= KPRE) { s_prefB = tid*4+3; s_cumB = acc+h0+h1+h2; }
            }
        }
        __syncthreads();
        const unsigned B = s_prefB, before = s_cumB;
        for (int i = tid; i < (int)M; i += NTHR) {      // second level -> hist2
            unsigned long long key = keybuf[i];
            if (((unsigned)(key >> (sh + 8)) & 0xFFu) == B)
                atomicAdd(&hist2[(unsigned)(key >> sh) & 0xFFu], 1u);
        }
        __syncthreads();
        if (tid < 64) {
            const unsigned target = KPRE - before;      // >= 1
            unsigned h0 = hist2[tid*4],   h1 = hist2[tid*4+1];
            unsigned h2 = hist2[tid*4+2], h3 = hist2[tid*4+3];
            unsigned lsum = h0 + h1 + h2 + h3;
            unsigned pre = lsum;
            #pragma unroll
            for (int off = 1; off < 64; off <<= 1) {
                unsigned v = __shfl_up(pre, off, 64);
                if (tid >= off) pre += v;
            }
            unsigned acc = pre - lsum;
            if (acc < target) {
                unsigned b2 = 256;
                if      (acc + h0           >= target) b2 = tid*4;
                else if (acc + h0 + h1      >= target) b2 = tid*4+1;
                else if (acc + h0 + h1 + h2 >= target) b2 = tid*4+2;
                else if (acc + lsum         >= target) b2 = tid*4+3;
                if (b2 < 256) sel_thr = (B << 8) | b2;
            }
        }
        __syncthreads();
        const unsigned thr = sel_thr;
        for (int i = tid; i < (int)M; i += NTHR) {
            unsigned long long key = keybuf[i];
            if (((unsigned)(key >> sh) & 0xFFFFu) <= thr) {
                unsigned pos = atomicAdd(&sel_cnt, 1u);
                if (pos < 512) sortbuf[pos] = key;
            }
        }
        __syncthreads();
    } else {
        for (int i = tid; i < (int)M; i += NTHR) sortbuf[i] = keybuf[i];
        if (tid == 0) sel_cnt = M;
        __syncthreads();
    }

    // ---- sort top candidates (ascending key == score desc, idx asc) --------
    const unsigned C2 = sel_cnt;
    unsigned long long* sorted;
    if (C2 <= 256) {
        // register/shfl bitonic-256 on waves 0-3 (wave-uniform guards)
        unsigned long long v = ~0ULL;
        if (tid < 256) {
            v = (tid < (int)C2) ? sortbuf[tid] : ~0ULL;
            #pragma unroll
            for (unsigned k = 2; k <= 64; k <<= 1) {
                for (unsigned j = k >> 1; j > 0; j >>= 1) {
                    unsigned long long o = shfl_xor_u64(v, (int)j);
                    bool tm = (((tid & k) == 0) == ((tid & j) == 0));
                    v = tm ? (v < o ? v : o) : (v > o ? v : o);
                }
            }
        }
        __syncthreads();
        if (tid < 256) sortbuf[tid] = v;
        __syncthreads();
        if (tid < 256) {           // k = 128: j = 64 via LDS, then shfl
            unsigned long long o = sortbuf[tid ^ 64];
            bool tm = (((tid & 128) == 0) == ((tid & 64) == 0));
            v = tm ? (v < o ? v : o) : (v > o ? v : o);
            #pragma unroll
            for (unsigned j = 32; j > 0; j >>= 1) {
                unsigned long long o2 = shfl_xor_u64(v, (int)j);
                bool t2 = (((tid & 128) == 0) == ((tid & j) == 0));
                v = t2 ? (v < o2 ? v : o2) : (v > o2 ? v : o2);
            }
        }
        __syncthreads();
        if (tid < 256) sortbuf[tid] = v;
        __syncthreads();
        if (tid < 256) {           // k = 256: j = 128 via LDS
            unsigned long long o = sortbuf[tid ^ 128];
            bool tm = ((tid & 128) == 0);
            v = tm ? (v < o ? v : o) : (v > o ? v : o);
        }
        __syncthreads();
        if (tid < 256) sortbuf[tid] = v;
        __syncthreads();
        if (tid < 256) {           // k = 256: j = 64 via LDS, then shfl
            unsigned long long o = sortbuf[tid ^ 64];
            bool tm = ((tid & 64) == 0);
            v = tm ? (v < o ? v : o) : (v > o ? v : o);
            #pragma unroll
            for (unsigned j = 32; j > 0; j >>= 1) {
                unsigned long long o2 = shfl_xor_u64(v, (int)j);
                bool t2 = ((tid & j) == 0);
                v = t2 ? (v < o2 ? v : o2) : (v > o2 ? v : o2);
            }
        }
        __syncthreads();
        if (tid < 256) sortbuf[tid] = v;
        __syncthreads();
        sorted = sortbuf;
    } else if (C2 <= 512) {
        for (int i = (int)C2 + tid; i < 512; i += NTHR) sortbuf[i] = ~0ULL;
        __syncthreads();
        bitonic_sort(sortbuf, 512, tid);
        sorted = sortbuf;
    } else {                                   // adversarial tie storm
        for (int i = (int)M + tid; i < CAP; i += NTHR) keybuf[i] = ~0ULL;
        __syncthreads();
        bitonic_sort(keybuf, CAP, tid);
        sorted = keybuf;
    }

    // ---- decode top-200 ----------------------------------------------------
    if (tid < KPRE) {
        unsigned long long key = sorted[tid];
        if (key != ~0ULL) {
            unsigned n = (unsigned)key;
            unsigned v = ~(unsigned)(key >> 32);
            v = (v >> 31) ? (v ^ 0x80000000u) : ~v;
            float x  = __uint_as_float(v);
            float sc = 1.0f / (1.0f + expf(-x));
            const float* bp = pred + (size_t)b * NA * 7 + (size_t)n * 7;
            float d0 = bp[0] * 0.1f, d1 = bp[1] * 0.1f;
            float d2 = bp[2] * 0.2f, d3 = bp[3] * 0.2f;
            float cx, cy, aw, ah;
            anchor_of((int)n, cx, cy, aw, ah);
            float xx = d0 * aw + cx;
            float yy = d1 * ah + cy;
            float ww = expf(d2) * aw;
            float hh = expf(d3) * ah;
            boxes[tid]    = make_float4(xx - ww * 0.5f, yy - hh * 0.5f,
                                        xx + ww * 0.5f, yy + hh * 0.5f);
            scores_s[tid] = sc;
        } else {
            boxes[tid]    = make_float4(0, 0, 0, 0);
            scores_s[tid] = -1.0f;
        }
    } else if (tid < 256) {
        scores_s[tid] = -1.0f;
    }
    __syncthreads();

    // ---- pairwise IoU bitmasks: (row, chunk) 2D decomposition --------------
    {
        const int row = tid & 255;
        const int cb  = tid >> 8;
        unsigned long long m = 0ULL;
        if (row < KPRE) {
            const int lo = cb * 64;
            const int hi = min(lo + 64, KPRE);
            float4 bi = boxes[row];
            float areai = (bi.z - bi.x) * (bi.w - bi.y);
            for (int j = max(row + 1, lo); j < hi; ++j) {
                float4 bj = boxes[j];
                float x1 = fmaxf(bi.x, bj.x), y1 = fmaxf(bi.y, bj.y);
                float x2 = fminf(bi.z, bj.z), y2 = fminf(bi.w, bj.w);
                float iw = fmaxf(x2 - x1, 0.0f), ih = fmaxf(y2 - y1, 0.0f);
                float inter = iw * ih;
                float areaj = (bj.z - bj.x) * (bj.w - bj.y);
                float uni   = fmaxf(areai + areaj - inter, 1e-8f);
                if (inter / uni > 0.5f) m |= 1ULL << (j - lo);
            }
        }
        mask[row][cb] = m;
    }
    __syncthreads();

    // ---- wave-parallel greedy sweep (wave 0), exact sequential semantics ---
    if (tid < 64) {
        unsigned long long keep[4];
        #pragma unroll
        for (int cb = 0; cb < 4; ++cb)
            keep[cb] = __ballot(scores_s[cb * 64 + lane] >= 0.05f);

        #pragma unroll
        for (int cb = 0; cb < 4; ++cb) {
            unsigned long long mw_self = mask[cb * 64 + lane][cb];
            unsigned long long kw   = keep[cb];
            // empty-mask rows can't suppress anyone -> skip them
            unsigned long long work = kw & __ballot(mw_self != 0ULL);
            while (work) {                       // uniform loop
                int t = __ffsll(work) - 1;
                work &= work - 1;
                if ((kw >> t) & 1ULL) {          // alive when its turn comes
                    unsigned long long m = __shfl(mw_self, t, 64);
                    kw   &= ~m;
                    work &= ~m;
                }
            }
            keep[cb] = kw;
            #pragma unroll
            for (int w = cb + 1; w < 4; ++w) {
                unsigned long long myw = mask[cb * 64 + lane][w];
                if ((__ballot(myw != 0ULL) & kw) == 0ULL) continue;
                unsigned long long contrib = ((kw >> lane) & 1ULL) ? myw : 0ULL;
                #pragma unroll
                for (int off = 1; off < 64; off <<= 1)
                    contrib |= __shfl_xor(contrib, off, 64);
                keep[w] &= ~contrib;
            }
        }

        if (lane == 0) {
            int k = 0;
            #pragma unroll
            for (int cb = 0; cb < 4; ++cb) {
                unsigned long long kw = keep[cb];
                while (kw && k < 10) {
                    int t = __ffsll(kw) - 1; kw &= kw - 1;
                    int i = cb * 64 + t;
                    s10[blk * 10 + k] = scores_s[i];
                    b10[blk * 10 + k] = boxes[i];
                    ++k;
                }
            }
            #pragma unroll
            for (int cb = 0; cb < 4; ++cb) {
                unsigned long long nk = ~keep[cb];
                if (cb == 3) nk &= 0xFFULL;          // i < 200
                while (nk && k < 10) {
                    int t = __ffsll(nk) - 1; nk &= nk - 1;
                    int i = cb * 64 + t;
                    s10[blk * 10 + k] = -1.0f;
                    b10[blk * 10 + k] = boxes[i];
                    ++k;
                }
            }
            // release this class's results to the merge block
            __threadfence();
            __hip_atomic_fetch_add(&done[b], 1u, __ATOMIC_RELEASE,
                                   __HIP_MEMORY_SCOPE_AGENT);
        }
    }
}

// ---------------- launch ----------------------------------------------------
extern "C" void kernel_launch(void* const* d_in, const int* in_sizes, int n_in,
                              void* d_out, int out_size, void* d_ws, size_t ws_size,
                              hipStream_t stream) {
    const float* pred = (const float*)d_in[1];   // d_in[0] = images (shape only)

    char* ws = (char*)d_ws;
    unsigned*            cnts = (unsigned*)           (ws + WS_CNT);
    unsigned long long*  keys = (unsigned long long*) (ws + WS_KEYS);
    float*               s10  = (float*)              (ws + WS_S10);
    float4*              b10  = (float4*)             (ws + WS_B10);
    unsigned*            done = (unsigned*)           (ws + WS_DONE);

    scan_kernel     <<<NB * NSLICE, STHR, 0, stream>>>(pred, cnts, keys, done);
    nms_merge_kernel<<<128, NTHR, 0, stream>>>(pred, cnts, keys, s10, b10, done,
                                               (float*)d_out);
}